// Round 2
// baseline (2929.129 us; speedup 1.0000x reference)
//
#include <hip/hip_runtime.h>
#include <hip/hip_bf16.h>

#define D_DIM 128
#define KT 128
#define JF 64
#define SCAN_CHUNK 1024

// ---------------------------------------------------------------------------
// hist: cnt_i[i]++ per edge; Xk (=segsum(edge_x,k)) and cntw via LDS privatize.
// ---------------------------------------------------------------------------
__global__ void __launch_bounds__(256) hist_kernel(
    const float* __restrict__ edge_x, const int* __restrict__ edge_i,
    const int* __restrict__ edge_k, unsigned* __restrict__ cnt_i,
    float* __restrict__ Xk, unsigned* __restrict__ cntw, int E, int nWavesTot)
{
    __shared__ float xk_s[KT * JF];      // 32 KB
    __shared__ unsigned cw_s[KT];
    for (int t = threadIdx.x; t < KT * JF; t += 256) xk_s[t] = 0.f;
    if (threadIdx.x < KT) cw_s[threadIdx.x] = 0u;
    __syncthreads();
    const int wid = threadIdx.x >> 6, lane = threadIdx.x & 63;
    const int g = blockIdx.x * 4 + wid;
    for (long e = g; e < (long)E; e += nWavesTot) {
        int i = edge_i[e], k = edge_k[e];
        float x = edge_x[e * 64 + lane];
        unsafeAtomicAdd(&xk_s[k * 64 + lane], x);
        if (lane == 0) {
            atomicAdd(&cnt_i[i], 1u);
            atomicAdd(&cw_s[k], 1u);
        }
    }
    __syncthreads();
    for (int t = threadIdx.x; t < KT * JF; t += 256)
        unsafeAtomicAdd(&Xk[t], xk_s[t]);
    if (threadIdx.x < KT && cw_s[threadIdx.x]) atomicAdd(&cntw[threadIdx.x], cw_s[threadIdx.x]);
}

// scan1: per-block (1024-elem chunk) totals
__global__ void scan1_kernel(const unsigned* __restrict__ cnt_i, unsigned* __restrict__ bsum, int n)
{
    __shared__ unsigned ts[256];
    int base = blockIdx.x * SCAN_CHUNK;
    unsigned s = 0;
    #pragma unroll
    for (int q = 0; q < 4; ++q) {
        int idx = base + threadIdx.x * 4 + q;
        if (idx < n) s += cnt_i[idx];
    }
    ts[threadIdx.x] = s;
    __syncthreads();
    for (int o = 128; o; o >>= 1) {
        if (threadIdx.x < o) ts[threadIdx.x] += ts[threadIdx.x + o];
        __syncthreads();
    }
    if (threadIdx.x == 0) bsum[blockIdx.x] = ts[0];
}

// scan2: serial exclusive scan of block sums (nb <= ~128); writes offs[n]=total
__global__ void scan2_kernel(const unsigned* __restrict__ bsum, unsigned* __restrict__ boff,
                             unsigned* __restrict__ offs, int nb, int n)
{
    if (threadIdx.x == 0) {
        unsigned run = 0;
        for (int b = 0; b < nb; ++b) { boff[b] = run; run += bsum[b]; }
        offs[n] = run;
    }
}

// scan3: per-element exclusive scan, write offs + cursor copy
__global__ void scan3_kernel(const unsigned* __restrict__ cnt_i, const unsigned* __restrict__ boff,
                             unsigned* __restrict__ offs, unsigned* __restrict__ cursor, int n)
{
    __shared__ unsigned ts[256];
    int base = blockIdx.x * SCAN_CHUNK;
    unsigned v[4], tsum = 0;
    #pragma unroll
    for (int q = 0; q < 4; ++q) {
        int idx = base + threadIdx.x * 4 + q;
        v[q] = (idx < n) ? cnt_i[idx] : 0u;
        tsum += v[q];
    }
    ts[threadIdx.x] = tsum;
    __syncthreads();
    for (int o = 1; o < 256; o <<= 1) {
        unsigned add = (threadIdx.x >= o) ? ts[threadIdx.x - o] : 0u;
        __syncthreads();
        ts[threadIdx.x] += add;
        __syncthreads();
    }
    unsigned run = ts[threadIdx.x] - tsum + boff[blockIdx.x];
    #pragma unroll
    for (int q = 0; q < 4; ++q) {
        int idx = base + threadIdx.x * 4 + q;
        if (idx < n) { offs[idx] = run; cursor[idx] = run; run += v[q]; }
    }
}

// scatter: sorted_e[pos] = e (pos unique via cursor atomic)
__global__ void scatter_kernel(const int* __restrict__ edge_i, unsigned* __restrict__ cursor,
                               int* __restrict__ sorted_e, int E)
{
    int e = blockIdx.x * 256 + threadIdx.x;
    if (e >= E) return;
    int i = edge_i[e];
    unsigned pos = atomicAdd(&cursor[i], 1u);
    sorted_e[pos] = e;
}

// build: wave per node. Xi row, Nmat8 row (u8 counts), cntraw, invcnt. No atomics.
__global__ void __launch_bounds__(256) build_kernel(
    const float* __restrict__ edge_x, const int* __restrict__ edge_k,
    const int* __restrict__ sorted_e, const unsigned* __restrict__ offs,
    float* __restrict__ Xi, unsigned char* __restrict__ Nmat8,
    float* __restrict__ cntraw, float* __restrict__ invcnt, int nNodes)
{
    __shared__ unsigned cnt_s[4][KT];
    const int wid = threadIdx.x >> 6, lane = threadIdx.x & 63;
    const int node = blockIdx.x * 4 + wid;
    if (node >= nNodes) return;
    cnt_s[wid][lane] = 0u;
    cnt_s[wid][lane + 64] = 0u;
    const int start = (int)offs[node], end = (int)offs[node + 1];
    const int deg = end - start;
    float xsum = 0.f;
    for (int c = 0; c < deg; c += 64) {
        int m = min(64, deg - c);
        int eid = 0, kid = 0;
        if (lane < m) { eid = sorted_e[start + c + lane]; kid = edge_k[eid]; }
        for (int t = 0; t < m; ++t) {
            int e = __shfl(eid, t);
            int k = __shfl(kid, t);
            xsum += edge_x[(long)e * 64 + lane];
            if (lane == 0) cnt_s[wid][k]++;
        }
    }
    Xi[(long)node * 64 + lane] = xsum;
    Nmat8[(long)node * 128 + lane]      = (unsigned char)cnt_s[wid][lane];
    Nmat8[(long)node * 128 + 64 + lane] = (unsigned char)cnt_s[wid][lane + 64];
    if (lane == 0) {
        cntraw[node] = (float)deg;
        invcnt[node] = 1.f / fmaxf((float)deg, 1.f);
    }
}

// ---------------------------------------------------------------------------
// layerA: U_out = relu( U_in@uWt + (N@P2 + Xi@P3)*invcnt + ub + flag*ebx )
// ---------------------------------------------------------------------------
__global__ void __launch_bounds__(256) layerA_kernel(
    const float* __restrict__ U_in, const unsigned char* __restrict__ Nmat8,
    const float* __restrict__ Xi, const float* __restrict__ cntraw,
    const float* __restrict__ invcnt, const float* __restrict__ uWt,
    const float* __restrict__ P2, const float* __restrict__ P3,
    const float* __restrict__ ub_l, const float* __restrict__ ebx,
    float* __restrict__ U_out, int nNodes)
{
    __shared__ __align__(16) float A_s[64][68];
    __shared__ __align__(16) float B_s[64][132];
    const int tid = threadIdx.x;
    const int tm = tid >> 5;
    const int td = tid & 31;
    float acc[8][4];
    #pragma unroll
    for (int a = 0; a < 8; ++a) { acc[a][0]=0.f; acc[a][1]=0.f; acc[a][2]=0.f; acc[a][3]=0.f; }
    const int nodeBase = blockIdx.x * 64;

    for (int tile = 0; tile < 5; ++tile) {
        __syncthreads();
        const float* Bsrc;
        if (tile == 0)      Bsrc = uWt;
        else if (tile == 1) Bsrc = uWt + 64 * 128;
        else if (tile == 2) Bsrc = P2;
        else if (tile == 3) Bsrc = P2 + 64 * 128;
        else                Bsrc = P3;
        #pragma unroll
        for (int it = 0; it < 32; ++it) {
            int t = tid + it * 256;
            int r = t >> 7, c = t & 127;
            B_s[r][c] = Bsrc[r * 128 + c];
        }
        #pragma unroll
        for (int it = 0; it < 16; ++it) {
            int t = tid + it * 256;
            int m = t >> 6, jj = t & 63;
            int node = nodeBase + m;
            float v = 0.f;
            if (node < nNodes) {
                if (tile < 2)      v = U_in[(long)node * 128 + tile * 64 + jj];
                else if (tile < 4) v = (float)Nmat8[(long)node * 128 + (tile - 2) * 64 + jj] * invcnt[node];
                else               v = Xi[(long)node * 64 + jj] * invcnt[node];
            }
            A_s[jj][m] = v;
        }
        __syncthreads();
        #pragma unroll 4
        for (int jj = 0; jj < 64; ++jj) {
            float4 bv = *(const float4*)&B_s[jj][td * 4];
            float4 a0 = *(const float4*)&A_s[jj][tm * 8];
            float4 a1 = *(const float4*)&A_s[jj][tm * 8 + 4];
            float av[8] = {a0.x, a0.y, a0.z, a0.w, a1.x, a1.y, a1.z, a1.w};
            #pragma unroll
            for (int a = 0; a < 8; ++a) {
                acc[a][0] += av[a] * bv.x;
                acc[a][1] += av[a] * bv.y;
                acc[a][2] += av[a] * bv.z;
                acc[a][3] += av[a] * bv.w;
            }
        }
    }
    const int d0 = td * 4;
    #pragma unroll
    for (int a = 0; a < 8; ++a) {
        int node = nodeBase + tm * 8 + a;
        if (node < nNodes) {
            float flag = (cntraw[node] > 0.f) ? 1.f : 0.f;
            float4 o;
            o.x = fmaxf(acc[a][0] + ub_l[d0 + 0] + flag * ebx[d0 + 0], 0.f);
            o.y = fmaxf(acc[a][1] + ub_l[d0 + 1] + flag * ebx[d0 + 1], 0.f);
            o.z = fmaxf(acc[a][2] + ub_l[d0 + 2] + flag * ebx[d0 + 2], 0.f);
            o.w = fmaxf(acc[a][3] + ub_l[d0 + 3] + flag * ebx[d0 + 3], 0.f);
            *(float4*)(U_out + (long)node * 128 + d0) = o;
        }
    }
}

// ---------------------------------------------------------------------------
// wmsgB: partial[block][k][d] = sum over node chunk of N[i][k]*U[i][d]
// ---------------------------------------------------------------------------
#define WB_BLOCKS 256
__global__ void __launch_bounds__(256) wmsgB_kernel(
    const float* __restrict__ U, const unsigned char* __restrict__ Nmat8,
    float* __restrict__ partial, int nodes_per_block, int nNodes)
{
    __shared__ __align__(16) float n_s[16][128];
    __shared__ __align__(16) float u_s[16][128];
    float acc[8][8];
    #pragma unroll
    for (int a = 0; a < 8; ++a)
        #pragma unroll
        for (int b = 0; b < 8; ++b) acc[a][b] = 0.f;
    const int kg = threadIdx.x >> 4;
    const int dg = threadIdx.x & 15;
    int base = blockIdx.x * nodes_per_block;
    int end = min(base + nodes_per_block, nNodes);
    for (int g = base; g < end; g += 16) {
        int cnt = min(16, end - g);
        __syncthreads();
        for (int t = threadIdx.x; t < 512; t += 256) {
            int r = t >> 5, c4 = t & 31;
            if (r < cnt) {
                uchar4 nb = *(const uchar4*)&Nmat8[(long)(g + r) * 128 + c4 * 4];
                float4 nf; nf.x = nb.x; nf.y = nb.y; nf.z = nb.z; nf.w = nb.w;
                *(float4*)&n_s[r][c4 * 4] = nf;
                *(float4*)&u_s[r][c4 * 4] = *(const float4*)&U[(long)(g + r) * 128 + c4 * 4];
            }
        }
        __syncthreads();
        for (int r = 0; r < cnt; ++r) {
            float4 n0 = *(const float4*)&n_s[r][kg * 8];
            float4 n1 = *(const float4*)&n_s[r][kg * 8 + 4];
            float4 u0v = *(const float4*)&u_s[r][dg * 8];
            float4 u1v = *(const float4*)&u_s[r][dg * 8 + 4];
            float nv[8] = {n0.x, n0.y, n0.z, n0.w, n1.x, n1.y, n1.z, n1.w};
            float uv[8] = {u0v.x, u0v.y, u0v.z, u0v.w, u1v.x, u1v.y, u1v.z, u1v.w};
            #pragma unroll
            for (int a = 0; a < 8; ++a)
                #pragma unroll
                for (int b = 0; b < 8; ++b) acc[a][b] += nv[a] * uv[b];
        }
    }
    float* my = partial + (size_t)blockIdx.x * 16384;
    #pragma unroll
    for (int a = 0; a < 8; ++a)
        #pragma unroll
        for (int b = 0; b < 8; ++b)
            my[(kg * 8 + a) * 128 + dg * 8 + b] = acc[a][b];
}

// reduce WB_BLOCKS partials -> Wmsg
__global__ void reduceP_kernel(const float* __restrict__ partial, float* __restrict__ Wmsg)
{
    int idx = blockIdx.x * 256 + threadIdx.x;   // 16384 total
    float s = 0.f;
    #pragma unroll 4
    for (int b = 0; b < WB_BLOCKS; ++b) s += partial[(size_t)b * 16384 + idx];
    Wmsg[idx] = s;
}

// Wmsgn[k][d] = (Wmsg + Xk@ep_W + cntw*ep_b) / max(cntw,1)
__global__ void wmsg_fin_kernel(const float* __restrict__ Wmsg, const float* __restrict__ Xk,
                                const unsigned* __restrict__ cntw, const float* __restrict__ ep_W,
                                const float* __restrict__ ep_b, float* __restrict__ out)
{
    int idx = blockIdx.x * 256 + threadIdx.x;
    int kk = idx >> 7, d = idx & 127;
    float s = Wmsg[idx];
    const float* xk = Xk + kk * 64;
    #pragma unroll 8
    for (int j = 0; j < 64; ++j) s += xk[j] * ep_W[j * 128 + d];
    float c = (float)cntw[kk];
    s += c * ep_b[d];
    out[idx] = s / fmaxf(c, 1.f);
}

// Generic small GEMM
__global__ void gemm_kernel(const float* __restrict__ A, const float* __restrict__ B,
                            const float* __restrict__ A2, const float* __restrict__ B2,
                            const float* __restrict__ bias, const float* __restrict__ res,
                            float* __restrict__ C, int M, int N, int K, int K2, int act)
{
    int idx = blockIdx.x * 256 + threadIdx.x;
    if (idx >= M * N) return;
    int m = idx / N, n = idx - m * N;
    float s = bias ? bias[n] : 0.f;
    const float* a = A + (long)m * K;
    for (int k = 0; k < K; ++k) s += a[k] * B[(long)k * N + n];
    if (A2) {
        const float* a2 = A2 + (long)m * K2;
        for (int k = 0; k < K2; ++k) s += a2[k] * B2[(long)k * N + n];
    }
    if (res) s += res[idx];
    if (act) s = fmaxf(s, 0.f);
    C[idx] = s;
}

__global__ void add_kernel(const float* __restrict__ A, const float* __restrict__ B,
                           float* __restrict__ C, int n)
{
    int i = blockIdx.x * 256 + threadIdx.x;
    if (i < n) C[i] = A[i] + B[i];
}

// MHA over 128 tokens, H=2, dh=64
__global__ void attn_kernel(const float* __restrict__ q, const float* __restrict__ kmat,
                            const float* __restrict__ vmat, float* __restrict__ outp)
{
    __shared__ float p_s[128];
    __shared__ float red_s[4];
    const int tok = blockIdx.x;
    const int t = threadIdx.x;
    const int lane = t & 63, wid = t >> 6;
    for (int h = 0; h < 2; ++h) {
        const float* qr = q + tok * 128 + h * 64;
        const float* kr = kmat + t * 128 + h * 64;
        float s = 0.f;
        #pragma unroll
        for (int d = 0; d < 64; ++d) s += qr[d] * kr[d];
        s *= 0.125f;
        float m = s;
        #pragma unroll
        for (int o = 32; o; o >>= 1) m = fmaxf(m, __shfl_down(m, o, 64));
        if (lane == 0) red_s[wid] = m;
        __syncthreads();
        m = fmaxf(red_s[0], red_s[1]);
        float ev = expf(s - m);
        float ss = ev;
        #pragma unroll
        for (int o = 32; o; o >>= 1) ss += __shfl_down(ss, o, 64);
        if (lane == 0) red_s[2 + wid] = ss;
        __syncthreads();
        float tot = red_s[2] + red_s[3];
        p_s[t] = ev / tot;
        __syncthreads();
        if (t < 64) {
            float o = 0.f;
            #pragma unroll 8
            for (int j = 0; j < 128; ++j) o += p_s[j] * vmat[j * 128 + h * 64 + t];
            outp[tok * 128 + h * 64 + t] = o;
        }
        __syncthreads();
    }
}

__global__ void ln_kernel(const float* __restrict__ x, const float* __restrict__ g,
                          const float* __restrict__ b, float* __restrict__ y)
{
    __shared__ float red_s[4];
    const int row = blockIdx.x, t = threadIdx.x, lane = t & 63, wid = t >> 6;
    float v = x[row * 128 + t];
    float s = v;
    #pragma unroll
    for (int o = 32; o; o >>= 1) s += __shfl_down(s, o, 64);
    if (lane == 0) red_s[wid] = s;
    __syncthreads();
    float mean = (red_s[0] + red_s[1]) * (1.f / 128.f);
    float d = v - mean;
    float q2 = d * d;
    #pragma unroll
    for (int o = 32; o; o >>= 1) q2 += __shfl_down(q2, o, 64);
    if (lane == 0) red_s[2 + wid] = q2;
    __syncthreads();
    float var = (red_s[2] + red_s[3]) * (1.f / 128.f);
    y[row * 128 + t] = d * rsqrtf(var + 1e-5f) * g[t] + b[t];
}

// decode: wave per triple, lane = 2 dims, coalesced row loads + shuffle reduce
__global__ void __launch_bounds__(256) decode_kernel(
    const int* __restrict__ idx_i, const int* __restrict__ idx_j, const int* __restrict__ idx_k,
    const float* __restrict__ U2, const float* __restrict__ Wf, const float* __restrict__ V,
    const float* __restrict__ bias, float* __restrict__ out, int n)
{
    const int wid = threadIdx.x >> 6, lane = threadIdx.x & 63;
    int t = blockIdx.x * 4 + wid;
    if (t >= n) return;
    int i = idx_i[t], j = idx_j[t], kk = idx_k[t];
    float2 u = *(const float2*)&U2[(long)i * 128 + lane * 2];
    float2 w = *(const float2*)&Wf[kk * 128 + lane * 2];
    float2 v = *(const float2*)&V[j * 128 + lane * 2];
    float s = u.x * w.x * v.x + u.y * w.y * v.y;
    #pragma unroll
    for (int o = 32; o; o >>= 1) s += __shfl_down(s, o, 64);
    if (lane == 0) out[t] = 1.f / (1.f + expf(-(s + bias[0])));
}

// ---------------------------------------------------------------------------
extern "C" void kernel_launch(void* const* d_in, const int* in_sizes, int n_in,
                              void* d_out, int out_size, void* d_ws, size_t ws_size,
                              hipStream_t stream)
{
    const float* edge_x = (const float*)d_in[0];
    const int*   edge_i = (const int*)d_in[1];
    const int*   edge_k = (const int*)d_in[2];
    const int*   idx_i  = (const int*)d_in[3];
    const int*   idx_j  = (const int*)d_in[4];
    const int*   idx_k  = (const int*)d_in[5];
    const float* u0   = (const float*)d_in[6];
    const float* w0   = (const float*)d_in[7];
    const float* ep_W = (const float*)d_in[8];
    const float* ep_b = (const float*)d_in[9];
    const float* uW   = (const float*)d_in[10];
    const float* ub   = (const float*)d_in[11];
    const float* wW   = (const float*)d_in[12];
    const float* wb   = (const float*)d_in[13];
    const float* pos  = (const float*)d_in[14];
    const float* Wq = (const float*)d_in[15];
    const float* Wk = (const float*)d_in[16];
    const float* Wv = (const float*)d_in[17];
    const float* bq = (const float*)d_in[18];
    const float* bk = (const float*)d_in[19];
    const float* bv = (const float*)d_in[20];
    const float* Wo = (const float*)d_in[21];
    const float* bo = (const float*)d_in[22];
    const float* ln1_g = (const float*)d_in[23];
    const float* ln1_b = (const float*)d_in[24];
    const float* f_W1 = (const float*)d_in[25];
    const float* f_b1 = (const float*)d_in[26];
    const float* f_W2 = (const float*)d_in[27];
    const float* f_b2 = (const float*)d_in[28];
    const float* ln2_g = (const float*)d_in[29];
    const float* ln2_b = (const float*)d_in[30];
    const float* Vmat = (const float*)d_in[31];
    const float* bias = (const float*)d_in[32];

    const int E   = in_sizes[1];
    const int NTt = in_sizes[3];
    const int nNodes = in_sizes[6] / D_DIM;
    const int nb = (nNodes + SCAN_CHUNK - 1) / SCAN_CHUNK;

    char* ws = (char*)d_ws;
    size_t off = 0;
    auto alloc = [&](size_t bytes) -> char* {
        char* p = ws + off;
        off = (off + bytes + 255) & ~(size_t)255;
        return p;
    };
    // zero-initialized region first
    unsigned* cnt_i = (unsigned*)alloc((size_t)nNodes * 4);
    float*    Xkseg = (float*)alloc(128 * 64 * 4);
    unsigned* cntw  = (unsigned*)alloc(512);
    size_t zeroBytes = off;
    // rest (written before read)
    unsigned* bsum   = (unsigned*)alloc(512 * 4);
    unsigned* boff   = (unsigned*)alloc(512 * 4);
    unsigned* offs   = (unsigned*)alloc((size_t)(nNodes + 1) * 4);
    unsigned* cursor = (unsigned*)alloc((size_t)nNodes * 4);
    int*      sorted_e = (int*)alloc((size_t)E * 4);
    unsigned char* Nmat8 = (unsigned char*)alloc((size_t)nNodes * 128);
    float* Xi = (float*)alloc((size_t)nNodes * 64 * 4);
    float* cntraw = (float*)alloc((size_t)nNodes * 4);
    float* invcnt = (float*)alloc((size_t)nNodes * 4);
    float* U1 = (float*)alloc((size_t)nNodes * 128 * 4);
    float* U2 = (float*)alloc((size_t)nNodes * 128 * 4);
    float* partials = (float*)alloc((size_t)WB_BLOCKS * 16384 * 4);
    float* Wmsg0 = (float*)alloc(65536);
    float* Wmsg1 = (float*)alloc(65536);
    float* W1 = (float*)alloc(65536);
    float* W2 = (float*)alloc(65536);
    float* P2_0 = (float*)alloc(65536);
    float* P2_1 = (float*)alloc(65536);
    float* P3_0 = (float*)alloc(32768);
    float* P3_1 = (float*)alloc(32768);
    float* ebx0 = (float*)alloc(512);
    float* ebx1 = (float*)alloc(512);
    float* Wmsgn0 = (float*)alloc(65536);
    float* Wmsgn1 = (float*)alloc(65536);
    float* Xmat  = (float*)alloc(65536);
    float* qm    = (float*)alloc(65536);
    float* km    = (float*)alloc(65536);
    float* vm    = (float*)alloc(65536);
    float* attnO = (float*)alloc(65536);
    float* pre1  = (float*)alloc(65536);
    float* H1m   = (float*)alloc(65536);
    float* F1    = (float*)alloc(262144);
    float* pre2  = (float*)alloc(65536);
    float* Wfm   = (float*)alloc(65536);

    const float* uWt0 = uW;
    const float* uWb0 = uW + 128 * 128;
    const float* uWt1 = uW + 256 * 128;
    const float* uWb1 = uW + 256 * 128 + 128 * 128;
    const float* wWt0 = wW;
    const float* wWb0 = wW + 128 * 128;
    const float* wWt1 = wW + 256 * 128;
    const float* wWb1 = wW + 256 * 128 + 128 * 128;

    hipMemsetAsync(d_ws, 0, zeroBytes, stream);

    // ---- sorted edge pipeline ----
    hist_kernel<<<512, 256, 0, stream>>>(edge_x, edge_i, edge_k, cnt_i, Xkseg, cntw, E, 512 * 4);
    scan1_kernel<<<nb, 256, 0, stream>>>(cnt_i, bsum, nNodes);
    scan2_kernel<<<1, 64, 0, stream>>>(bsum, boff, offs, nb, nNodes);
    scan3_kernel<<<nb, 256, 0, stream>>>(cnt_i, boff, offs, cursor, nNodes);
    scatter_kernel<<<(E + 255) / 256, 256, 0, stream>>>(edge_i, cursor, sorted_e, E);
    build_kernel<<<(nNodes + 3) / 4, 256, 0, stream>>>(edge_x, edge_k, sorted_e, offs,
                                                       Xi, Nmat8, cntraw, invcnt, nNodes);

    int npb = (nNodes + WB_BLOCKS - 1) / WB_BLOCKS;

    // ---- layer 0 ----
    gemm_kernel<<<64, 256, 0, stream>>>(w0, uWb0, nullptr, nullptr, nullptr, nullptr, P2_0, 128, 128, 128, 0, 0);
    gemm_kernel<<<32, 256, 0, stream>>>(ep_W, uWb0, nullptr, nullptr, nullptr, nullptr, P3_0, 64, 128, 128, 0, 0);
    gemm_kernel<<<1, 256, 0, stream>>>(ep_b, uWb0, nullptr, nullptr, nullptr, nullptr, ebx0, 1, 128, 128, 0, 0);
    wmsgB_kernel<<<WB_BLOCKS, 256, 0, stream>>>(u0, Nmat8, partials, npb, nNodes);
    reduceP_kernel<<<64, 256, 0, stream>>>(partials, Wmsg0);
    layerA_kernel<<<(nNodes + 63) / 64, 256, 0, stream>>>(u0, Nmat8, Xi, cntraw, invcnt,
                                                          uWt0, P2_0, P3_0, ub, ebx0, U1, nNodes);
    wmsg_fin_kernel<<<64, 256, 0, stream>>>(Wmsg0, Xkseg, cntw, ep_W, ep_b, Wmsgn0);
    gemm_kernel<<<64, 256, 0, stream>>>(w0, wWt0, Wmsgn0, wWb0, wb, nullptr, W1, 128, 128, 128, 128, 1);

    // ---- layer 1 ----
    gemm_kernel<<<64, 256, 0, stream>>>(W1, uWb1, nullptr, nullptr, nullptr, nullptr, P2_1, 128, 128, 128, 0, 0);
    gemm_kernel<<<32, 256, 0, stream>>>(ep_W, uWb1, nullptr, nullptr, nullptr, nullptr, P3_1, 64, 128, 128, 0, 0);
    gemm_kernel<<<1, 256, 0, stream>>>(ep_b, uWb1, nullptr, nullptr, nullptr, nullptr, ebx1, 1, 128, 128, 0, 0);
    wmsgB_kernel<<<WB_BLOCKS, 256, 0, stream>>>(U1, Nmat8, partials, npb, nNodes);
    reduceP_kernel<<<64, 256, 0, stream>>>(partials, Wmsg1);
    layerA_kernel<<<(nNodes + 63) / 64, 256, 0, stream>>>(U1, Nmat8, Xi, cntraw, invcnt,
                                                          uWt1, P2_1, P3_1, ub + 128, ebx1, U2, nNodes);
    wmsg_fin_kernel<<<64, 256, 0, stream>>>(Wmsg1, Xkseg, cntw, ep_W, ep_b, Wmsgn1);
    gemm_kernel<<<64, 256, 0, stream>>>(W1, wWt1, Wmsgn1, wWb1, wb + 128, nullptr, W2, 128, 128, 128, 128, 1);

    // ---- TimeRefine ----
    add_kernel<<<64, 256, 0, stream>>>(W2, pos, Xmat, 128 * 128);
    gemm_kernel<<<64, 256, 0, stream>>>(Xmat, Wq, nullptr, nullptr, bq, nullptr, qm, 128, 128, 128, 0, 0);
    gemm_kernel<<<64, 256, 0, stream>>>(Xmat, Wk, nullptr, nullptr, bk, nullptr, km, 128, 128, 128, 0, 0);
    gemm_kernel<<<64, 256, 0, stream>>>(Xmat, Wv, nullptr, nullptr, bv, nullptr, vm, 128, 128, 128, 0, 0);
    attn_kernel<<<128, 128, 0, stream>>>(qm, km, vm, attnO);
    gemm_kernel<<<64, 256, 0, stream>>>(attnO, Wo, nullptr, nullptr, bo, Xmat, pre1, 128, 128, 128, 0, 0);
    ln_kernel<<<128, 128, 0, stream>>>(pre1, ln1_g, ln1_b, H1m);
    gemm_kernel<<<256, 256, 0, stream>>>(H1m, f_W1, nullptr, nullptr, f_b1, nullptr, F1, 128, 512, 128, 0, 1);
    gemm_kernel<<<64, 256, 0, stream>>>(F1, f_W2, nullptr, nullptr, f_b2, H1m, pre2, 128, 128, 512, 0, 0);
    ln_kernel<<<128, 128, 0, stream>>>(pre2, ln2_g, ln2_b, Wfm);

    // ---- decode ----
    decode_kernel<<<(NTt + 3) / 4, 256, 0, stream>>>(idx_i, idx_j, idx_k, U2, Wfm, Vmat,
                                                     bias, (float*)d_out, NTt);
}

// Round 3
// 1906.605 us; speedup vs baseline: 1.5363x; 1.5363x over previous
//
#include <hip/hip_runtime.h>
#include <hip/hip_bf16.h>

#define D_DIM 128
#define KT 128
#define JF 64
#define SCAN_CHUNK 1024
#define WB_BLOCKS 256

typedef __attribute__((ext_vector_type(8))) short bf16x8;
typedef __attribute__((ext_vector_type(4))) float f32x4;

__device__ inline unsigned short f2b(float f) {
    __hip_bfloat16 h = __float2bfloat16(f);
    return *reinterpret_cast<unsigned short*>(&h);
}

// ---------------------------------------------------------------------------
// hist: cnt_i histogram (global atomics) + cntw (LDS privatized). No edge_x.
// ---------------------------------------------------------------------------
__global__ void __launch_bounds__(256) hist_kernel(
    const int* __restrict__ edge_i, const int* __restrict__ edge_k,
    unsigned* __restrict__ cnt_i, unsigned* __restrict__ cntw, int E)
{
    __shared__ unsigned cw_s[KT];
    if (threadIdx.x < KT) cw_s[threadIdx.x] = 0u;
    __syncthreads();
    int e = blockIdx.x * 256 + threadIdx.x;
    if (e < E) {
        atomicAdd(&cnt_i[edge_i[e]], 1u);
        atomicAdd(&cw_s[edge_k[e]], 1u);
    }
    __syncthreads();
    if (threadIdx.x < KT && cw_s[threadIdx.x]) atomicAdd(&cntw[threadIdx.x], cw_s[threadIdx.x]);
}

// scan1: per-chunk totals
__global__ void scan1_kernel(const unsigned* __restrict__ cnt_i, unsigned* __restrict__ bsum, int n)
{
    __shared__ unsigned ts[256];
    int base = blockIdx.x * SCAN_CHUNK;
    unsigned s = 0;
    #pragma unroll
    for (int q = 0; q < 4; ++q) {
        int idx = base + threadIdx.x * 4 + q;
        if (idx < n) s += cnt_i[idx];
    }
    ts[threadIdx.x] = s;
    __syncthreads();
    for (int o = 128; o; o >>= 1) {
        if (threadIdx.x < o) ts[threadIdx.x] += ts[threadIdx.x + o];
        __syncthreads();
    }
    if (threadIdx.x == 0) bsum[blockIdx.x] = ts[0];
}

__global__ void scan2_kernel(const unsigned* __restrict__ bsum, unsigned* __restrict__ boff,
                             unsigned* __restrict__ offs, int nb, int n)
{
    if (threadIdx.x == 0) {
        unsigned run = 0;
        for (int b = 0; b < nb; ++b) { boff[b] = run; run += bsum[b]; }
        offs[n] = run;
    }
}

__global__ void scan3_kernel(const unsigned* __restrict__ cnt_i, const unsigned* __restrict__ boff,
                             unsigned* __restrict__ offs, unsigned* __restrict__ cursor, int n)
{
    __shared__ unsigned ts[256];
    int base = blockIdx.x * SCAN_CHUNK;
    unsigned v[4], tsum = 0;
    #pragma unroll
    for (int q = 0; q < 4; ++q) {
        int idx = base + threadIdx.x * 4 + q;
        v[q] = (idx < n) ? cnt_i[idx] : 0u;
        tsum += v[q];
    }
    ts[threadIdx.x] = tsum;
    __syncthreads();
    for (int o = 1; o < 256; o <<= 1) {
        unsigned add = (threadIdx.x >= o) ? ts[threadIdx.x - o] : 0u;
        __syncthreads();
        ts[threadIdx.x] += add;
        __syncthreads();
    }
    unsigned run = ts[threadIdx.x] - tsum + boff[blockIdx.x];
    #pragma unroll
    for (int q = 0; q < 4; ++q) {
        int idx = base + threadIdx.x * 4 + q;
        if (idx < n) { offs[idx] = run; cursor[idx] = run; run += v[q]; }
    }
}

__global__ void scatter_kernel(const int* __restrict__ edge_i, unsigned* __restrict__ cursor,
                               int* __restrict__ sorted_e, int E)
{
    int e = blockIdx.x * 256 + threadIdx.x;
    if (e >= E) return;
    int i = edge_i[e];
    unsigned pos = atomicAdd(&cursor[i], 1u);
    sorted_e[pos] = e;
}

// ---------------------------------------------------------------------------
// build: wave per node (strided). Xi row, Nmat8 row, cntraw/invcnt, and Xk
// accumulated in LDS (flushed once per block). 4-deep load unroll for ILP.
// ---------------------------------------------------------------------------
__global__ void __launch_bounds__(256) build_kernel(
    const float* __restrict__ edge_x, const int* __restrict__ edge_k,
    const int* __restrict__ sorted_e, const unsigned* __restrict__ offs,
    float* __restrict__ Xi, unsigned char* __restrict__ Nmat8,
    float* __restrict__ cntraw, float* __restrict__ invcnt,
    float* __restrict__ Xk, int nNodes, int nWavesTot)
{
    __shared__ float xk_s[KT * JF];      // 32 KB
    __shared__ unsigned cnt_s[4][KT];
    for (int t = threadIdx.x; t < KT * JF; t += 256) xk_s[t] = 0.f;
    __syncthreads();
    const int wid = threadIdx.x >> 6, lane = threadIdx.x & 63;
    for (int node = blockIdx.x * 4 + wid; node < nNodes; node += nWavesTot) {
        cnt_s[wid][lane] = 0u;
        cnt_s[wid][lane + 64] = 0u;
        const int start = (int)offs[node], end = (int)offs[node + 1];
        const int deg = end - start;
        float xsum = 0.f;
        for (int c = 0; c < deg; c += 64) {
            int m = min(64, deg - c);
            int eid = 0, kid = 0;
            if (lane < m) {
                eid = sorted_e[start + c + lane];
                kid = edge_k[eid];
                atomicAdd(&cnt_s[wid][kid], 1u);
            }
            int t = 0;
            for (; t + 4 <= m; t += 4) {
                int e0 = __shfl(eid, t),   e1 = __shfl(eid, t+1);
                int e2 = __shfl(eid, t+2), e3 = __shfl(eid, t+3);
                int k0 = __shfl(kid, t),   k1 = __shfl(kid, t+1);
                int k2 = __shfl(kid, t+2), k3 = __shfl(kid, t+3);
                float x0 = edge_x[(long)e0 * 64 + lane];
                float x1 = edge_x[(long)e1 * 64 + lane];
                float x2 = edge_x[(long)e2 * 64 + lane];
                float x3 = edge_x[(long)e3 * 64 + lane];
                unsafeAtomicAdd(&xk_s[k0 * 64 + lane], x0);
                unsafeAtomicAdd(&xk_s[k1 * 64 + lane], x1);
                unsafeAtomicAdd(&xk_s[k2 * 64 + lane], x2);
                unsafeAtomicAdd(&xk_s[k3 * 64 + lane], x3);
                xsum += x0 + x1 + x2 + x3;
            }
            for (; t < m; ++t) {
                int e0 = __shfl(eid, t);
                int k0 = __shfl(kid, t);
                float x0 = edge_x[(long)e0 * 64 + lane];
                unsafeAtomicAdd(&xk_s[k0 * 64 + lane], x0);
                xsum += x0;
            }
        }
        Xi[(long)node * 64 + lane] = xsum;
        Nmat8[(long)node * 128 + lane]      = (unsigned char)cnt_s[wid][lane];
        Nmat8[(long)node * 128 + 64 + lane] = (unsigned char)cnt_s[wid][lane + 64];
        if (lane == 0) {
            cntraw[node] = (float)deg;
            invcnt[node] = 1.f / fmaxf((float)deg, 1.f);
        }
    }
    __syncthreads();
    for (int t = threadIdx.x; t < KT * JF; t += 256)
        unsafeAtomicAdd(&Xk[t], xk_s[t]);
}

// ---------------------------------------------------------------------------
// btprep: Bt[n][k] = B[k][n] in bf16, B = [uWt(128); P2(128); P3(64)] rows
// ---------------------------------------------------------------------------
__global__ void btprep_kernel(const float* __restrict__ uWt, const float* __restrict__ P2,
                              const float* __restrict__ P3, unsigned short* __restrict__ Bt)
{
    int idx = blockIdx.x * 256 + threadIdx.x;
    if (idx >= 128 * 320) return;
    int n = idx / 320, k = idx - n * 320;
    float v = (k < 128) ? uWt[k * 128 + n] : (k < 256) ? P2[(k - 128) * 128 + n]
                                                       : P3[(k - 256) * 128 + n];
    Bt[idx] = f2b(v);
}

// ---------------------------------------------------------------------------
// layerA MFMA: U_out[128-node tile] = relu(A[128x320]@B[320x128] + ub + flag*ebx)
// A = [U | N*inv | Xi*inv] staged fp32->bf16; B from Bt (bf16, [n][k]).
// ---------------------------------------------------------------------------
__global__ void __launch_bounds__(256) layerA_mfma(
    const float* __restrict__ U_in, const unsigned char* __restrict__ Nmat8,
    const float* __restrict__ Xi, const float* __restrict__ cntraw,
    const float* __restrict__ invcnt, const unsigned short* __restrict__ Bt,
    const float* __restrict__ ub_l, const float* __restrict__ ebx,
    float* __restrict__ U_out, int nNodes)
{
    __shared__ __align__(16) unsigned short A_s[128][40];
    __shared__ __align__(16) unsigned short B_s[128][40];
    const int tid = threadIdx.x;
    const int w = tid >> 6, lane = tid & 63;
    const int quad = lane >> 4, l16 = lane & 15;
    const int nodeBase = blockIdx.x * 128;
    f32x4 acc[2][8];
    #pragma unroll
    for (int a = 0; a < 2; ++a)
        #pragma unroll
        for (int b = 0; b < 8; ++b) acc[a][b] = (f32x4){0.f, 0.f, 0.f, 0.f};

    const int rr = tid >> 3;          // 0..31
    const int kc = (tid & 7) * 4;     // 0..28

    for (int ks = 0; ks < 10; ++ks) {
        const int k0 = ks * 32;
        __syncthreads();
        // stage B tile (from L2-resident Bt)
        {
            int n = tid & 127, seg = tid >> 7;
            const unsigned short* src = Bt + n * 320 + k0 + seg * 16;
            uint4 p0 = *(const uint4*)(src);
            uint4 p1 = *(const uint4*)(src + 8);
            *(uint4*)&B_s[n][seg * 16]     = p0;
            *(uint4*)&B_s[n][seg * 16 + 8] = p1;
        }
        // stage A tile 128x32 (convert fp32 -> bf16)
        #pragma unroll
        for (int p = 0; p < 4; ++p) {
            int r = p * 32 + rr;
            int node = nodeBase + r;
            float4 v = {0.f, 0.f, 0.f, 0.f};
            if (node < nNodes) {
                if (ks < 4) {
                    v = *(const float4*)&U_in[(long)node * 128 + k0 + kc];
                } else if (ks < 8) {
                    float inv = invcnt[node];
                    const unsigned char* np_ = &Nmat8[(long)node * 128 + (k0 - 128) + kc];
                    v.x = (float)np_[0] * inv; v.y = (float)np_[1] * inv;
                    v.z = (float)np_[2] * inv; v.w = (float)np_[3] * inv;
                } else {
                    float inv = invcnt[node];
                    float4 x = *(const float4*)&Xi[(long)node * 64 + (k0 - 256) + kc];
                    v.x = x.x * inv; v.y = x.y * inv; v.z = x.z * inv; v.w = x.w * inv;
                }
            }
            ushort4 w4 = make_ushort4(f2b(v.x), f2b(v.y), f2b(v.z), f2b(v.w));
            *(ushort4*)&A_s[r][kc] = w4;
        }
        __syncthreads();
        bf16x8 a0 = *(const bf16x8*)&A_s[w * 32 + l16][quad * 8];
        bf16x8 a1 = *(const bf16x8*)&A_s[w * 32 + 16 + l16][quad * 8];
        #pragma unroll
        for (int nt = 0; nt < 8; ++nt) {
            bf16x8 b = *(const bf16x8*)&B_s[nt * 16 + l16][quad * 8];
            acc[0][nt] = __builtin_amdgcn_mfma_f32_16x16x32_bf16(a0, b, acc[0][nt], 0, 0, 0);
            acc[1][nt] = __builtin_amdgcn_mfma_f32_16x16x32_bf16(a1, b, acc[1][nt], 0, 0, 0);
        }
    }
    // epilogue: row = w*32 + mt*16 + quad*4 + r, col = nt*16 + l16
    #pragma unroll
    for (int mt = 0; mt < 2; ++mt) {
        #pragma unroll
        for (int r = 0; r < 4; ++r) {
            int row = w * 32 + mt * 16 + quad * 4 + r;
            int node = nodeBase + row;
            if (node < nNodes) {
                float flag = (cntraw[node] > 0.f) ? 1.f : 0.f;
                #pragma unroll
                for (int nt = 0; nt < 8; ++nt) {
                    int col = nt * 16 + l16;
                    float vv = acc[mt][nt][r] + ub_l[col] + flag * ebx[col];
                    U_out[(long)node * 128 + col] = fmaxf(vv, 0.f);
                }
            }
        }
    }
}

// ---------------------------------------------------------------------------
// wmsgB MFMA: partial[b] = N^T_chunk @ U_chunk  (M=128 tokens, N=128 dims, K=nodes)
// ---------------------------------------------------------------------------
__global__ void __launch_bounds__(256) wmsgB_mfma(
    const float* __restrict__ U, const unsigned char* __restrict__ Nmat8,
    float* __restrict__ partial, int nodes_per_block, int nNodes)
{
    __shared__ __align__(16) unsigned short A_s[128][40];  // [ktok][node]
    __shared__ __align__(16) unsigned short B_s[128][40];  // [d][node]
    const int tid = threadIdx.x;
    const int w = tid >> 6, lane = tid & 63;
    const int quad = lane >> 4, l16 = lane & 15;
    f32x4 acc[2][8];
    #pragma unroll
    for (int a = 0; a < 2; ++a)
        #pragma unroll
        for (int b = 0; b < 8; ++b) acc[a][b] = (f32x4){0.f, 0.f, 0.f, 0.f};

    int base = blockIdx.x * nodes_per_block;
    int end = min(base + nodes_per_block, nNodes);
    const int nn = tid >> 3;          // 0..31  node slot
    const int cc = (tid & 7) * 16;    // 0..112 row chunk
    for (int g = base; g < end; g += 32) {
        int cnt = min(32, end - g);
        __syncthreads();
        if (nn < cnt) {
            int node = g + nn;
            uint4 nb = *(const uint4*)&Nmat8[(long)node * 128 + cc];
            const unsigned char* nbp = (const unsigned char*)&nb;
            float4 u4[4];
            #pragma unroll
            for (int q = 0; q < 4; ++q)
                u4[q] = *(const float4*)&U[(long)node * 128 + cc + q * 4];
            const float* up = (const float*)u4;
            #pragma unroll
            for (int j = 0; j < 16; ++j) {
                A_s[cc + j][nn] = f2b((float)nbp[j]);
                B_s[cc + j][nn] = f2b(up[j]);
            }
        } else {
            #pragma unroll
            for (int j = 0; j < 16; ++j) { A_s[cc + j][nn] = 0; B_s[cc + j][nn] = 0; }
        }
        __syncthreads();
        bf16x8 a0 = *(const bf16x8*)&A_s[w * 32 + l16][quad * 8];
        bf16x8 a1 = *(const bf16x8*)&A_s[w * 32 + 16 + l16][quad * 8];
        #pragma unroll
        for (int nt = 0; nt < 8; ++nt) {
            bf16x8 b = *(const bf16x8*)&B_s[nt * 16 + l16][quad * 8];
            acc[0][nt] = __builtin_amdgcn_mfma_f32_16x16x32_bf16(a0, b, acc[0][nt], 0, 0, 0);
            acc[1][nt] = __builtin_amdgcn_mfma_f32_16x16x32_bf16(a1, b, acc[1][nt], 0, 0, 0);
        }
    }
    float* my = partial + (size_t)blockIdx.x * 16384;
    #pragma unroll
    for (int mt = 0; mt < 2; ++mt)
        #pragma unroll
        for (int r = 0; r < 4; ++r) {
            int row = w * 32 + mt * 16 + quad * 4 + r;
            #pragma unroll
            for (int nt = 0; nt < 8; ++nt)
                my[row * 128 + nt * 16 + l16] = acc[mt][nt][r];
        }
}

__global__ void reduceP_kernel(const float* __restrict__ partial, float* __restrict__ Wmsg)
{
    int idx = blockIdx.x * 256 + threadIdx.x;
    float s = 0.f;
    #pragma unroll 4
    for (int b = 0; b < WB_BLOCKS; ++b) s += partial[(size_t)b * 16384 + idx];
    Wmsg[idx] = s;
}

__global__ void wmsg_fin_kernel(const float* __restrict__ Wmsg, const float* __restrict__ Xk,
                                const unsigned* __restrict__ cntw, const float* __restrict__ ep_W,
                                const float* __restrict__ ep_b, float* __restrict__ out)
{
    int idx = blockIdx.x * 256 + threadIdx.x;
    int kk = idx >> 7, d = idx & 127;
    float s = Wmsg[idx];
    const float* xk = Xk + kk * 64;
    #pragma unroll 8
    for (int j = 0; j < 64; ++j) s += xk[j] * ep_W[j * 128 + d];
    float c = (float)cntw[kk];
    s += c * ep_b[d];
    out[idx] = s / fmaxf(c, 1.f);
}

__global__ void gemm_kernel(const float* __restrict__ A, const float* __restrict__ B,
                            const float* __restrict__ A2, const float* __restrict__ B2,
                            const float* __restrict__ bias, const float* __restrict__ res,
                            float* __restrict__ C, int M, int N, int K, int K2, int act)
{
    int idx = blockIdx.x * 256 + threadIdx.x;
    if (idx >= M * N) return;
    int m = idx / N, n = idx - m * N;
    float s = bias ? bias[n] : 0.f;
    const float* a = A + (long)m * K;
    for (int k = 0; k < K; ++k) s += a[k] * B[(long)k * N + n];
    if (A2) {
        const float* a2 = A2 + (long)m * K2;
        for (int k = 0; k < K2; ++k) s += a2[k] * B2[(long)k * N + n];
    }
    if (res) s += res[idx];
    if (act) s = fmaxf(s, 0.f);
    C[idx] = s;
}

__global__ void add_kernel(const float* __restrict__ A, const float* __restrict__ B,
                           float* __restrict__ C, int n)
{
    int i = blockIdx.x * 256 + threadIdx.x;
    if (i < n) C[i] = A[i] + B[i];
}

__global__ void attn_kernel(const float* __restrict__ q, const float* __restrict__ kmat,
                            const float* __restrict__ vmat, float* __restrict__ outp)
{
    __shared__ float p_s[128];
    __shared__ float red_s[4];
    const int tok = blockIdx.x;
    const int t = threadIdx.x;
    const int lane = t & 63, wid = t >> 6;
    for (int h = 0; h < 2; ++h) {
        const float* qr = q + tok * 128 + h * 64;
        const float* kr = kmat + t * 128 + h * 64;
        float s = 0.f;
        #pragma unroll
        for (int d = 0; d < 64; ++d) s += qr[d] * kr[d];
        s *= 0.125f;
        float m = s;
        #pragma unroll
        for (int o = 32; o; o >>= 1) m = fmaxf(m, __shfl_down(m, o, 64));
        if (lane == 0) red_s[wid] = m;
        __syncthreads();
        m = fmaxf(red_s[0], red_s[1]);
        float ev = expf(s - m);
        float ss = ev;
        #pragma unroll
        for (int o = 32; o; o >>= 1) ss += __shfl_down(ss, o, 64);
        if (lane == 0) red_s[2 + wid] = ss;
        __syncthreads();
        float tot = red_s[2] + red_s[3];
        p_s[t] = ev / tot;
        __syncthreads();
        if (t < 64) {
            float o = 0.f;
            #pragma unroll 8
            for (int j = 0; j < 128; ++j) o += p_s[j] * vmat[j * 128 + h * 64 + t];
            outp[tok * 128 + h * 64 + t] = o;
        }
        __syncthreads();
    }
}

__global__ void ln_kernel(const float* __restrict__ x, const float* __restrict__ g,
                          const float* __restrict__ b, float* __restrict__ y)
{
    __shared__ float red_s[4];
    const int row = blockIdx.x, t = threadIdx.x, lane = t & 63, wid = t >> 6;
    float v = x[row * 128 + t];
    float s = v;
    #pragma unroll
    for (int o = 32; o; o >>= 1) s += __shfl_down(s, o, 64);
    if (lane == 0) red_s[wid] = s;
    __syncthreads();
    float mean = (red_s[0] + red_s[1]) * (1.f / 128.f);
    float d = v - mean;
    float q2 = d * d;
    #pragma unroll
    for (int o = 32; o; o >>= 1) q2 += __shfl_down(q2, o, 64);
    if (lane == 0) red_s[2 + wid] = q2;
    __syncthreads();
    float var = (red_s[2] + red_s[3]) * (1.f / 128.f);
    y[row * 128 + t] = d * rsqrtf(var + 1e-5f) * g[t] + b[t];
}

// decode: 2 triples per wave (32-lane halves), float4 coalesced rows
__global__ void __launch_bounds__(256) decode_kernel(
    const int* __restrict__ idx_i, const int* __restrict__ idx_j, const int* __restrict__ idx_k,
    const float* __restrict__ U2, const float* __restrict__ Wf, const float* __restrict__ V,
    const float* __restrict__ bias, float* __restrict__ out, int n)
{
    const int wid = threadIdx.x >> 6, lane = threadIdx.x & 63;
    const int half = lane >> 5, hl = lane & 31;
    int t = blockIdx.x * 8 + wid * 2 + half;
    if (t >= n) return;
    int i = idx_i[t], j = idx_j[t], kk = idx_k[t];
    float4 u = *(const float4*)&U2[(long)i * 128 + hl * 4];
    float4 w = *(const float4*)&Wf[kk * 128 + hl * 4];
    float4 v = *(const float4*)&V[j * 128 + hl * 4];
    float s = u.x * w.x * v.x + u.y * w.y * v.y + u.z * w.z * v.z + u.w * w.w * v.w;
    #pragma unroll
    for (int o = 16; o; o >>= 1) s += __shfl_down(s, o, 64);
    if (hl == 0) out[t] = 1.f / (1.f + expf(-(s + bias[0])));
}

// ---------------------------------------------------------------------------
extern "C" void kernel_launch(void* const* d_in, const int* in_sizes, int n_in,
                              void* d_out, int out_size, void* d_ws, size_t ws_size,
                              hipStream_t stream)
{
    const float* edge_x = (const float*)d_in[0];
    const int*   edge_i = (const int*)d_in[1];
    const int*   edge_k = (const int*)d_in[2];
    const int*   idx_i  = (const int*)d_in[3];
    const int*   idx_j  = (const int*)d_in[4];
    const int*   idx_k  = (const int*)d_in[5];
    const float* u0   = (const float*)d_in[6];
    const float* w0   = (const float*)d_in[7];
    const float* ep_W = (const float*)d_in[8];
    const float* ep_b = (const float*)d_in[9];
    const float* uW   = (const float*)d_in[10];
    const float* ub   = (const float*)d_in[11];
    const float* wW   = (const float*)d_in[12];
    const float* wb   = (const float*)d_in[13];
    const float* pos  = (const float*)d_in[14];
    const float* Wq = (const float*)d_in[15];
    const float* Wk = (const float*)d_in[16];
    const float* Wv = (const float*)d_in[17];
    const float* bq = (const float*)d_in[18];
    const float* bk = (const float*)d_in[19];
    const float* bv = (const float*)d_in[20];
    const float* Wo = (const float*)d_in[21];
    const float* bo = (const float*)d_in[22];
    const float* ln1_g = (const float*)d_in[23];
    const float* ln1_b = (const float*)d_in[24];
    const float* f_W1 = (const float*)d_in[25];
    const float* f_b1 = (const float*)d_in[26];
    const float* f_W2 = (const float*)d_in[27];
    const float* f_b2 = (const float*)d_in[28];
    const float* ln2_g = (const float*)d_in[29];
    const float* ln2_b = (const float*)d_in[30];
    const float* Vmat = (const float*)d_in[31];
    const float* bias = (const float*)d_in[32];

    const int E   = in_sizes[1];
    const int NTt = in_sizes[3];
    const int nNodes = in_sizes[6] / D_DIM;
    const int nb = (nNodes + SCAN_CHUNK - 1) / SCAN_CHUNK;

    char* ws = (char*)d_ws;
    size_t off = 0;
    auto alloc = [&](size_t bytes) -> char* {
        char* p = ws + off;
        off = (off + bytes + 255) & ~(size_t)255;
        return p;
    };
    // zero-initialized region first
    unsigned* cnt_i = (unsigned*)alloc((size_t)nNodes * 4);
    float*    Xkseg = (float*)alloc(128 * 64 * 4);
    unsigned* cntw  = (unsigned*)alloc(512);
    size_t zeroBytes = off;
    // rest (written before read)
    unsigned* bsum   = (unsigned*)alloc(512 * 4);
    unsigned* boff   = (unsigned*)alloc(512 * 4);
    unsigned* offs   = (unsigned*)alloc((size_t)(nNodes + 1) * 4);
    unsigned* cursor = (unsigned*)alloc((size_t)nNodes * 4);
    int*      sorted_e = (int*)alloc((size_t)E * 4);
    unsigned char* Nmat8 = (unsigned char*)alloc((size_t)nNodes * 128);
    float* Xi = (float*)alloc((size_t)nNodes * 64 * 4);
    float* cntraw = (float*)alloc((size_t)nNodes * 4);
    float* invcnt = (float*)alloc((size_t)nNodes * 4);
    float* U1 = (float*)alloc((size_t)nNodes * 128 * 4);
    float* U2 = (float*)alloc((size_t)nNodes * 128 * 4);
    float* partials = (float*)alloc((size_t)WB_BLOCKS * 16384 * 4);
    unsigned short* Bt0 = (unsigned short*)alloc(128 * 320 * 2);
    unsigned short* Bt1 = (unsigned short*)alloc(128 * 320 * 2);
    float* Wmsg0 = (float*)alloc(65536);
    float* Wmsg1 = (float*)alloc(65536);
    float* W1 = (float*)alloc(65536);
    float* W2 = (float*)alloc(65536);
    float* P2_0 = (float*)alloc(65536);
    float* P2_1 = (float*)alloc(65536);
    float* P3_0 = (float*)alloc(32768);
    float* P3_1 = (float*)alloc(32768);
    float* ebx0 = (float*)alloc(512);
    float* ebx1 = (float*)alloc(512);
    float* Wmsgn0 = (float*)alloc(65536);
    float* Wmsgn1 = (float*)alloc(65536);
    float* Xmat  = (float*)alloc(65536);
    float* qm    = (float*)alloc(65536);
    float* km    = (float*)alloc(65536);
    float* vm    = (float*)alloc(65536);
    float* attnO = (float*)alloc(65536);
    float* pre1  = (float*)alloc(65536);
    float* H1m   = (float*)alloc(65536);
    float* F1    = (float*)alloc(262144);
    float* pre2  = (float*)alloc(65536);
    float* Wfm   = (float*)alloc(65536);

    const float* uWt0 = uW;
    const float* uWb0 = uW + 128 * 128;
    const float* uWt1 = uW + 256 * 128;
    const float* uWb1 = uW + 256 * 128 + 128 * 128;
    const float* wWt0 = wW;
    const float* wWb0 = wW + 128 * 128;
    const float* wWt1 = wW + 256 * 128;
    const float* wWb1 = wW + 256 * 128 + 128 * 128;

    hipMemsetAsync(d_ws, 0, zeroBytes, stream);

    // ---- sorted edge pipeline ----
    hist_kernel<<<(E + 255) / 256, 256, 0, stream>>>(edge_i, edge_k, cnt_i, cntw, E);
    scan1_kernel<<<nb, 256, 0, stream>>>(cnt_i, bsum, nNodes);
    scan2_kernel<<<1, 64, 0, stream>>>(bsum, boff, offs, nb, nNodes);
    scan3_kernel<<<nb, 256, 0, stream>>>(cnt_i, boff, offs, cursor, nNodes);
    scatter_kernel<<<(E + 255) / 256, 256, 0, stream>>>(edge_i, cursor, sorted_e, E);
    build_kernel<<<512, 256, 0, stream>>>(edge_x, edge_k, sorted_e, offs,
                                          Xi, Nmat8, cntraw, invcnt, Xkseg, nNodes, 2048);

    int npb = (nNodes + WB_BLOCKS - 1) / WB_BLOCKS;
    int la_grid = (nNodes + 127) / 128;

    // ---- layer 0 ----
    gemm_kernel<<<64, 256, 0, stream>>>(w0, uWb0, nullptr, nullptr, nullptr, nullptr, P2_0, 128, 128, 128, 0, 0);
    gemm_kernel<<<32, 256, 0, stream>>>(ep_W, uWb0, nullptr, nullptr, nullptr, nullptr, P3_0, 64, 128, 128, 0, 0);
    gemm_kernel<<<1, 256, 0, stream>>>(ep_b, uWb0, nullptr, nullptr, nullptr, nullptr, ebx0, 1, 128, 128, 0, 0);
    btprep_kernel<<<160, 256, 0, stream>>>(uWt0, P2_0, P3_0, Bt0);
    wmsgB_mfma<<<WB_BLOCKS, 256, 0, stream>>>(u0, Nmat8, partials, npb, nNodes);
    reduceP_kernel<<<64, 256, 0, stream>>>(partials, Wmsg0);
    layerA_mfma<<<la_grid, 256, 0, stream>>>(u0, Nmat8, Xi, cntraw, invcnt, Bt0, ub, ebx0, U1, nNodes);
    wmsg_fin_kernel<<<64, 256, 0, stream>>>(Wmsg0, Xkseg, cntw, ep_W, ep_b, Wmsgn0);
    gemm_kernel<<<64, 256, 0, stream>>>(w0, wWt0, Wmsgn0, wWb0, wb, nullptr, W1, 128, 128, 128, 128, 1);

    // ---- layer 1 ----
    gemm_kernel<<<64, 256, 0, stream>>>(W1, uWb1, nullptr, nullptr, nullptr, nullptr, P2_1, 128, 128, 128, 0, 0);
    gemm_kernel<<<32, 256, 0, stream>>>(ep_W, uWb1, nullptr, nullptr, nullptr, nullptr, P3_1, 64, 128, 128, 0, 0);
    gemm_kernel<<<1, 256, 0, stream>>>(ep_b, uWb1, nullptr, nullptr, nullptr, nullptr, ebx1, 1, 128, 128, 0, 0);
    btprep_kernel<<<160, 256, 0, stream>>>(uWt1, P2_1, P3_1, Bt1);
    wmsgB_mfma<<<WB_BLOCKS, 256, 0, stream>>>(U1, Nmat8, partials, npb, nNodes);
    reduceP_kernel<<<64, 256, 0, stream>>>(partials, Wmsg1);
    layerA_mfma<<<la_grid, 256, 0, stream>>>(U1, Nmat8, Xi, cntraw, invcnt, Bt1, ub + 128, ebx1, U2, nNodes);
    wmsg_fin_kernel<<<64, 256, 0, stream>>>(Wmsg1, Xkseg, cntw, ep_W, ep_b, Wmsgn1);
    gemm_kernel<<<64, 256, 0, stream>>>(W1, wWt1, Wmsgn1, wWb1, wb + 128, nullptr, W2, 128, 128, 128, 128, 1);

    // ---- TimeRefine ----
    add_kernel<<<64, 256, 0, stream>>>(W2, pos, Xmat, 128 * 128);
    gemm_kernel<<<64, 256, 0, stream>>>(Xmat, Wq, nullptr, nullptr, bq, nullptr, qm, 128, 128, 128, 0, 0);
    gemm_kernel<<<64, 256, 0, stream>>>(Xmat, Wk, nullptr, nullptr, bk, nullptr, km, 128, 128, 128, 0, 0);
    gemm_kernel<<<64, 256, 0, stream>>>(Xmat, Wv, nullptr, nullptr, bv, nullptr, vm, 128, 128, 128, 0, 0);
    attn_kernel<<<128, 128, 0, stream>>>(qm, km, vm, attnO);
    gemm_kernel<<<64, 256, 0, stream>>>(attnO, Wo, nullptr, nullptr, bo, Xmat, pre1, 128, 128, 128, 0, 0);
    ln_kernel<<<128, 128, 0, stream>>>(pre1, ln1_g, ln1_b, H1m);
    gemm_kernel<<<256, 256, 0, stream>>>(H1m, f_W1, nullptr, nullptr, f_b1, nullptr, F1, 128, 512, 128, 0, 1);
    gemm_kernel<<<64, 256, 0, stream>>>(F1, f_W2, nullptr, nullptr, f_b2, H1m, pre2, 128, 128, 512, 0, 0);
    ln_kernel<<<128, 128, 0, stream>>>(pre2, ln2_g, ln2_b, Wfm);

    // ---- decode ----
    decode_kernel<<<(NTt + 7) / 8, 256, 0, stream>>>(idx_i, idx_j, idx_k, U2, Wfm, Vmat,
                                                     bias, (float*)d_out, NTt);
}

// Round 4
// 1899.765 us; speedup vs baseline: 1.5418x; 1.0036x over previous
//
#include <hip/hip_runtime.h>
#include <hip/hip_bf16.h>

#define D_DIM 128
#define KT 128
#define JF 64
#define SCAN_CHUNK 1024
#define WB_BLOCKS 256

typedef __attribute__((ext_vector_type(8))) short bf16x8;
typedef __attribute__((ext_vector_type(4))) float f32x4;

__device__ inline unsigned short f2b(float f) {
    __hip_bfloat16 h = __float2bfloat16(f);
    return *reinterpret_cast<unsigned short*>(&h);
}

// ---------------------------------------------------------------------------
// hist: cnt_i histogram (global atomics) + cntw (LDS privatized).
// ---------------------------------------------------------------------------
__global__ void __launch_bounds__(256) hist_kernel(
    const int* __restrict__ edge_i, const int* __restrict__ edge_k,
    unsigned* __restrict__ cnt_i, unsigned* __restrict__ cntw, int E)
{
    __shared__ unsigned cw_s[KT];
    if (threadIdx.x < KT) cw_s[threadIdx.x] = 0u;
    __syncthreads();
    int e = blockIdx.x * 256 + threadIdx.x;
    if (e < E) {
        atomicAdd(&cnt_i[edge_i[e]], 1u);
        atomicAdd(&cw_s[edge_k[e]], 1u);
    }
    __syncthreads();
    if (threadIdx.x < KT && cw_s[threadIdx.x]) atomicAdd(&cntw[threadIdx.x], cw_s[threadIdx.x]);
}

__global__ void scan1_kernel(const unsigned* __restrict__ cnt_i, unsigned* __restrict__ bsum, int n)
{
    __shared__ unsigned ts[256];
    int base = blockIdx.x * SCAN_CHUNK;
    unsigned s = 0;
    #pragma unroll
    for (int q = 0; q < 4; ++q) {
        int idx = base + threadIdx.x * 4 + q;
        if (idx < n) s += cnt_i[idx];
    }
    ts[threadIdx.x] = s;
    __syncthreads();
    for (int o = 128; o; o >>= 1) {
        if (threadIdx.x < o) ts[threadIdx.x] += ts[threadIdx.x + o];
        __syncthreads();
    }
    if (threadIdx.x == 0) bsum[blockIdx.x] = ts[0];
}

__global__ void scan2_kernel(const unsigned* __restrict__ bsum, unsigned* __restrict__ boff,
                             unsigned* __restrict__ offs, int nb, int n)
{
    if (threadIdx.x == 0) {
        unsigned run = 0;
        for (int b = 0; b < nb; ++b) { boff[b] = run; run += bsum[b]; }
        offs[n] = run;
    }
}

__global__ void scan3_kernel(const unsigned* __restrict__ cnt_i, const unsigned* __restrict__ boff,
                             unsigned* __restrict__ offs, unsigned* __restrict__ cursor, int n)
{
    __shared__ unsigned ts[256];
    int base = blockIdx.x * SCAN_CHUNK;
    unsigned v[4], tsum = 0;
    #pragma unroll
    for (int q = 0; q < 4; ++q) {
        int idx = base + threadIdx.x * 4 + q;
        v[q] = (idx < n) ? cnt_i[idx] : 0u;
        tsum += v[q];
    }
    ts[threadIdx.x] = tsum;
    __syncthreads();
    for (int o = 1; o < 256; o <<= 1) {
        unsigned add = (threadIdx.x >= o) ? ts[threadIdx.x - o] : 0u;
        __syncthreads();
        ts[threadIdx.x] += add;
        __syncthreads();
    }
    unsigned run = ts[threadIdx.x] - tsum + boff[blockIdx.x];
    #pragma unroll
    for (int q = 0; q < 4; ++q) {
        int idx = base + threadIdx.x * 4 + q;
        if (idx < n) { offs[idx] = run; cursor[idx] = run; run += v[q]; }
    }
}

// scatter: sorted_ek[pos] = (e, k)
__global__ void scatter_kernel(const int* __restrict__ edge_i, const int* __restrict__ edge_k,
                               unsigned* __restrict__ cursor, int2* __restrict__ sorted_ek, int E)
{
    int e = blockIdx.x * 256 + threadIdx.x;
    if (e >= E) return;
    int i = edge_i[e];
    int k = edge_k[e];
    unsigned pos = atomicAdd(&cursor[i], 1u);
    sorted_ek[pos] = make_int2(e, k);
}

// ---------------------------------------------------------------------------
// build: wave per contiguous node range. Xi row, Nmat8 row, cntraw/invcnt, Xk
// (LDS-accumulated). 8-deep independent edge_x loads for latency hiding.
// ---------------------------------------------------------------------------
__global__ void __launch_bounds__(256) build_kernel(
    const float* __restrict__ edge_x, const int2* __restrict__ sorted_ek,
    const unsigned* __restrict__ offs,
    float* __restrict__ Xi, unsigned char* __restrict__ Nmat8,
    float* __restrict__ cntraw, float* __restrict__ invcnt,
    float* __restrict__ Xk, int nNodes, int nodes_per_wave)
{
    __shared__ float xk_s[KT * JF];      // 32 KB
    __shared__ unsigned cnt_s[4][KT];
    for (int t = threadIdx.x; t < KT * JF; t += 256) xk_s[t] = 0.f;
    __syncthreads();
    const int wid = threadIdx.x >> 6, lane = threadIdx.x & 63;
    const int gw = blockIdx.x * 4 + wid;
    const int n0 = gw * nodes_per_wave;
    const int n1 = min(n0 + nodes_per_wave, nNodes);
    for (int node = n0; node < n1; ++node) {
        cnt_s[wid][lane] = 0u;
        cnt_s[wid][lane + 64] = 0u;
        const int start = (int)offs[node], end = (int)offs[node + 1];
        const int deg = end - start;
        float xsum = 0.f;
        for (int c = 0; c < deg; c += 64) {
            int m = min(64, deg - c);
            int2 ek = make_int2(0, 0);
            if (lane < m) {
                ek = sorted_ek[start + c + lane];
                atomicAdd(&cnt_s[wid][ek.y], 1u);
            }
            for (int t = 0; t < m; t += 8) {
                int tm = min(8, m - t);
                int ee[8], kk[8];
                float x[8];
                #pragma unroll
                for (int q = 0; q < 8; ++q) {
                    ee[q] = __shfl(ek.x, t + q);
                    kk[q] = __shfl(ek.y, t + q);
                }
                #pragma unroll
                for (int q = 0; q < 8; ++q)
                    x[q] = (q < tm) ? edge_x[(long)ee[q] * 64 + lane] : 0.f;
                #pragma unroll
                for (int q = 0; q < 8; ++q) {
                    if (q < tm) {
                        unsafeAtomicAdd(&xk_s[kk[q] * 64 + lane], x[q]);
                        xsum += x[q];
                    }
                }
            }
        }
        Xi[(long)node * 64 + lane] = xsum;
        Nmat8[(long)node * 128 + lane]      = (unsigned char)cnt_s[wid][lane];
        Nmat8[(long)node * 128 + 64 + lane] = (unsigned char)cnt_s[wid][lane + 64];
        if (lane == 0) {
            cntraw[node] = (float)deg;
            invcnt[node] = 1.f / fmaxf((float)deg, 1.f);
        }
    }
    __syncthreads();
    for (int t = threadIdx.x; t < KT * JF; t += 256)
        unsafeAtomicAdd(&Xk[t], xk_s[t]);
}

// ---------------------------------------------------------------------------
// btprep: Bt[n][k] = B[k][n] in bf16, B = [uWt(128); P2(128); P3(64)] rows
// ---------------------------------------------------------------------------
__global__ void btprep_kernel(const float* __restrict__ uWt, const float* __restrict__ P2,
                              const float* __restrict__ P3, unsigned short* __restrict__ Bt)
{
    int idx = blockIdx.x * 256 + threadIdx.x;
    if (idx >= 128 * 320) return;
    int n = idx / 320, k = idx - n * 320;
    float v = (k < 128) ? uWt[k * 128 + n] : (k < 256) ? P2[(k - 128) * 128 + n]
                                                       : P3[(k - 256) * 128 + n];
    Bt[idx] = f2b(v);
}

// ---------------------------------------------------------------------------
// layerA MFMA: U_out[128-node tile] = relu(A[128x320]@B[320x128] + ub + flag*ebx)
// ---------------------------------------------------------------------------
__global__ void __launch_bounds__(256) layerA_mfma(
    const float* __restrict__ U_in, const unsigned char* __restrict__ Nmat8,
    const float* __restrict__ Xi, const float* __restrict__ cntraw,
    const float* __restrict__ invcnt, const unsigned short* __restrict__ Bt,
    const float* __restrict__ ub_l, const float* __restrict__ ebx,
    float* __restrict__ U_out, int nNodes)
{
    __shared__ __align__(16) unsigned short A_s[128][40];
    __shared__ __align__(16) unsigned short B_s[128][40];
    const int tid = threadIdx.x;
    const int w = tid >> 6, lane = tid & 63;
    const int quad = lane >> 4, l16 = lane & 15;
    const int nodeBase = blockIdx.x * 128;
    f32x4 acc[2][8];
    #pragma unroll
    for (int a = 0; a < 2; ++a)
        #pragma unroll
        for (int b = 0; b < 8; ++b) acc[a][b] = (f32x4){0.f, 0.f, 0.f, 0.f};

    const int rr = tid >> 3;          // 0..31
    const int kc = (tid & 7) * 4;     // 0..28

    for (int ks = 0; ks < 10; ++ks) {
        const int k0 = ks * 32;
        __syncthreads();
        {
            int n = tid & 127, seg = tid >> 7;
            const unsigned short* src = Bt + n * 320 + k0 + seg * 16;
            uint4 p0 = *(const uint4*)(src);
            uint4 p1 = *(const uint4*)(src + 8);
            *(uint4*)&B_s[n][seg * 16]     = p0;
            *(uint4*)&B_s[n][seg * 16 + 8] = p1;
        }
        #pragma unroll
        for (int p = 0; p < 4; ++p) {
            int r = p * 32 + rr;
            int node = nodeBase + r;
            float4 v = {0.f, 0.f, 0.f, 0.f};
            if (node < nNodes) {
                if (ks < 4) {
                    v = *(const float4*)&U_in[(long)node * 128 + k0 + kc];
                } else if (ks < 8) {
                    float inv = invcnt[node];
                    const unsigned char* np_ = &Nmat8[(long)node * 128 + (k0 - 128) + kc];
                    v.x = (float)np_[0] * inv; v.y = (float)np_[1] * inv;
                    v.z = (float)np_[2] * inv; v.w = (float)np_[3] * inv;
                } else {
                    float inv = invcnt[node];
                    float4 x = *(const float4*)&Xi[(long)node * 64 + (k0 - 256) + kc];
                    v.x = x.x * inv; v.y = x.y * inv; v.z = x.z * inv; v.w = x.w * inv;
                }
            }
            ushort4 w4 = make_ushort4(f2b(v.x), f2b(v.y), f2b(v.z), f2b(v.w));
            *(ushort4*)&A_s[r][kc] = w4;
        }
        __syncthreads();
        bf16x8 a0 = *(const bf16x8*)&A_s[w * 32 + l16][quad * 8];
        bf16x8 a1 = *(const bf16x8*)&A_s[w * 32 + 16 + l16][quad * 8];
        #pragma unroll
        for (int nt = 0; nt < 8; ++nt) {
            bf16x8 b = *(const bf16x8*)&B_s[nt * 16 + l16][quad * 8];
            acc[0][nt] = __builtin_amdgcn_mfma_f32_16x16x32_bf16(a0, b, acc[0][nt], 0, 0, 0);
            acc[1][nt] = __builtin_amdgcn_mfma_f32_16x16x32_bf16(a1, b, acc[1][nt], 0, 0, 0);
        }
    }
    #pragma unroll
    for (int mt = 0; mt < 2; ++mt) {
        #pragma unroll
        for (int r = 0; r < 4; ++r) {
            int row = w * 32 + mt * 16 + quad * 4 + r;
            int node = nodeBase + row;
            if (node < nNodes) {
                float flag = (cntraw[node] > 0.f) ? 1.f : 0.f;
                #pragma unroll
                for (int nt = 0; nt < 8; ++nt) {
                    int col = nt * 16 + l16;
                    float vv = acc[mt][nt][r] + ub_l[col] + flag * ebx[col];
                    U_out[(long)node * 128 + col] = fmaxf(vv, 0.f);
                }
            }
        }
    }
}

// ---------------------------------------------------------------------------
// wmsgB MFMA: partial[b] = N^T_chunk @ U_chunk
// ---------------------------------------------------------------------------
__global__ void __launch_bounds__(256) wmsgB_mfma(
    const float* __restrict__ U, const unsigned char* __restrict__ Nmat8,
    float* __restrict__ partial, int nodes_per_block, int nNodes)
{
    __shared__ __align__(16) unsigned short A_s[128][40];  // [ktok][node]
    __shared__ __align__(16) unsigned short B_s[128][40];  // [d][node]
    const int tid = threadIdx.x;
    const int w = tid >> 6, lane = tid & 63;
    const int quad = lane >> 4, l16 = lane & 15;
    f32x4 acc[2][8];
    #pragma unroll
    for (int a = 0; a < 2; ++a)
        #pragma unroll
        for (int b = 0; b < 8; ++b) acc[a][b] = (f32x4){0.f, 0.f, 0.f, 0.f};

    int base = blockIdx.x * nodes_per_block;
    int end = min(base + nodes_per_block, nNodes);
    const int nn = tid >> 3;          // 0..31
    const int cc = (tid & 7) * 16;    // 0..112
    for (int g = base; g < end; g += 32) {
        int cnt = min(32, end - g);
        __syncthreads();
        if (nn < cnt) {
            int node = g + nn;
            uint4 nb = *(const uint4*)&Nmat8[(long)node * 128 + cc];
            const unsigned char* nbp = (const unsigned char*)&nb;
            float4 u4[4];
            #pragma unroll
            for (int q = 0; q < 4; ++q)
                u4[q] = *(const float4*)&U[(long)node * 128 + cc + q * 4];
            const float* up = (const float*)u4;
            #pragma unroll
            for (int j = 0; j < 16; ++j) {
                A_s[cc + j][nn] = f2b((float)nbp[j]);
                B_s[cc + j][nn] = f2b(up[j]);
            }
        } else {
            #pragma unroll
            for (int j = 0; j < 16; ++j) { A_s[cc + j][nn] = 0; B_s[cc + j][nn] = 0; }
        }
        __syncthreads();
        bf16x8 a0 = *(const bf16x8*)&A_s[w * 32 + l16][quad * 8];
        bf16x8 a1 = *(const bf16x8*)&A_s[w * 32 + 16 + l16][quad * 8];
        #pragma unroll
        for (int nt = 0; nt < 8; ++nt) {
            bf16x8 b = *(const bf16x8*)&B_s[nt * 16 + l16][quad * 8];
            acc[0][nt] = __builtin_amdgcn_mfma_f32_16x16x32_bf16(a0, b, acc[0][nt], 0, 0, 0);
            acc[1][nt] = __builtin_amdgcn_mfma_f32_16x16x32_bf16(a1, b, acc[1][nt], 0, 0, 0);
        }
    }
    float* my = partial + (size_t)blockIdx.x * 16384;
    #pragma unroll
    for (int mt = 0; mt < 2; ++mt)
        #pragma unroll
        for (int r = 0; r < 4; ++r) {
            int row = w * 32 + mt * 16 + quad * 4 + r;
            #pragma unroll
            for (int nt = 0; nt < 8; ++nt)
                my[row * 128 + nt * 16 + l16] = acc[mt][nt][r];
        }
}

__global__ void reduceP_kernel(const float* __restrict__ partial, float* __restrict__ Wmsg)
{
    int idx = blockIdx.x * 256 + threadIdx.x;
    float s = 0.f;
    #pragma unroll 4
    for (int b = 0; b < WB_BLOCKS; ++b) s += partial[(size_t)b * 16384 + idx];
    Wmsg[idx] = s;
}

__global__ void wmsg_fin_kernel(const float* __restrict__ Wmsg, const float* __restrict__ Xk,
                                const unsigned* __restrict__ cntw, const float* __restrict__ ep_W,
                                const float* __restrict__ ep_b, float* __restrict__ out)
{
    int idx = blockIdx.x * 256 + threadIdx.x;
    int kk = idx >> 7, d = idx & 127;
    float s = Wmsg[idx];
    const float* xk = Xk + kk * 64;
    #pragma unroll 8
    for (int j = 0; j < 64; ++j) s += xk[j] * ep_W[j * 128 + d];
    float c = (float)cntw[kk];
    s += c * ep_b[d];
    out[idx] = s / fmaxf(c, 1.f);
}

__global__ void gemm_kernel(const float* __restrict__ A, const float* __restrict__ B,
                            const float* __restrict__ A2, const float* __restrict__ B2,
                            const float* __restrict__ bias, const float* __restrict__ res,
                            float* __restrict__ C, int M, int N, int K, int K2, int act)
{
    int idx = blockIdx.x * 256 + threadIdx.x;
    if (idx >= M * N) return;
    int m = idx / N, n = idx - m * N;
    float s = bias ? bias[n] : 0.f;
    const float* a = A + (long)m * K;
    for (int k = 0; k < K; ++k) s += a[k] * B[(long)k * N + n];
    if (A2) {
        const float* a2 = A2 + (long)m * K2;
        for (int k = 0; k < K2; ++k) s += a2[k] * B2[(long)k * N + n];
    }
    if (res) s += res[idx];
    if (act) s = fmaxf(s, 0.f);
    C[idx] = s;
}

__global__ void add_kernel(const float* __restrict__ A, const float* __restrict__ B,
                           float* __restrict__ C, int n)
{
    int i = blockIdx.x * 256 + threadIdx.x;
    if (i < n) C[i] = A[i] + B[i];
}

__global__ void attn_kernel(const float* __restrict__ q, const float* __restrict__ kmat,
                            const float* __restrict__ vmat, float* __restrict__ outp)
{
    __shared__ float p_s[128];
    __shared__ float red_s[4];
    const int tok = blockIdx.x;
    const int t = threadIdx.x;
    const int lane = t & 63, wid = t >> 6;
    for (int h = 0; h < 2; ++h) {
        const float* qr = q + tok * 128 + h * 64;
        const float* kr = kmat + t * 128 + h * 64;
        float s = 0.f;
        #pragma unroll
        for (int d = 0; d < 64; ++d) s += qr[d] * kr[d];
        s *= 0.125f;
        float m = s;
        #pragma unroll
        for (int o = 32; o; o >>= 1) m = fmaxf(m, __shfl_down(m, o, 64));
        if (lane == 0) red_s[wid] = m;
        __syncthreads();
        m = fmaxf(red_s[0], red_s[1]);
        float ev = expf(s - m);
        float ss = ev;
        #pragma unroll
        for (int o = 32; o; o >>= 1) ss += __shfl_down(ss, o, 64);
        if (lane == 0) red_s[2 + wid] = ss;
        __syncthreads();
        float tot = red_s[2] + red_s[3];
        p_s[t] = ev / tot;
        __syncthreads();
        if (t < 64) {
            float o = 0.f;
            #pragma unroll 8
            for (int j = 0; j < 128; ++j) o += p_s[j] * vmat[j * 128 + h * 64 + t];
            outp[tok * 128 + h * 64 + t] = o;
        }
        __syncthreads();
    }
}

__global__ void ln_kernel(const float* __restrict__ x, const float* __restrict__ g,
                          const float* __restrict__ b, float* __restrict__ y)
{
    __shared__ float red_s[4];
    const int row = blockIdx.x, t = threadIdx.x, lane = t & 63, wid = t >> 6;
    float v = x[row * 128 + t];
    float s = v;
    #pragma unroll
    for (int o = 32; o; o >>= 1) s += __shfl_down(s, o, 64);
    if (lane == 0) red_s[wid] = s;
    __syncthreads();
    float mean = (red_s[0] + red_s[1]) * (1.f / 128.f);
    float d = v - mean;
    float q2 = d * d;
    #pragma unroll
    for (int o = 32; o; o >>= 1) q2 += __shfl_down(q2, o, 64);
    if (lane == 0) red_s[2 + wid] = q2;
    __syncthreads();
    float var = (red_s[2] + red_s[3]) * (1.f / 128.f);
    y[row * 128 + t] = d * rsqrtf(var + 1e-5f) * g[t] + b[t];
}

// decode: 16 lanes per triple (4 triples/wave), float4 pairs, width-16 reduce
__global__ void __launch_bounds__(256) decode_kernel(
    const int* __restrict__ idx_i, const int* __restrict__ idx_j, const int* __restrict__ idx_k,
    const float* __restrict__ U2, const float* __restrict__ Wf, const float* __restrict__ V,
    const float* __restrict__ bias, float* __restrict__ out, int n)
{
    const int g = threadIdx.x >> 4;      // 0..15
    const int hl = threadIdx.x & 15;
    int t = blockIdx.x * 16 + g;
    if (t >= n) return;
    int i = idx_i[t], j = idx_j[t], kk = idx_k[t];
    const float* up = U2 + (long)i * 128 + hl * 8;
    const float* wp = Wf + kk * 128 + hl * 8;
    const float* vp = V + j * 128 + hl * 8;
    float4 u0 = *(const float4*)up,       u1 = *(const float4*)(up + 4);
    float4 w0 = *(const float4*)wp,       w1 = *(const float4*)(wp + 4);
    float4 v0 = *(const float4*)vp,       v1 = *(const float4*)(vp + 4);
    float s = u0.x * w0.x * v0.x + u0.y * w0.y * v0.y + u0.z * w0.z * v0.z + u0.w * w0.w * v0.w
            + u1.x * w1.x * v1.x + u1.y * w1.y * v1.y + u1.z * w1.z * v1.z + u1.w * w1.w * v1.w;
    #pragma unroll
    for (int o = 8; o; o >>= 1) s += __shfl_down(s, o, 16);
    if (hl == 0) out[t] = 1.f / (1.f + expf(-(s + bias[0])));
}

// ---------------------------------------------------------------------------
extern "C" void kernel_launch(void* const* d_in, const int* in_sizes, int n_in,
                              void* d_out, int out_size, void* d_ws, size_t ws_size,
                              hipStream_t stream)
{
    const float* edge_x = (const float*)d_in[0];
    const int*   edge_i = (const int*)d_in[1];
    const int*   edge_k = (const int*)d_in[2];
    const int*   idx_i  = (const int*)d_in[3];
    const int*   idx_j  = (const int*)d_in[4];
    const int*   idx_k  = (const int*)d_in[5];
    const float* u0   = (const float*)d_in[6];
    const float* w0   = (const float*)d_in[7];
    const float* ep_W = (const float*)d_in[8];
    const float* ep_b = (const float*)d_in[9];
    const float* uW   = (const float*)d_in[10];
    const float* ub   = (const float*)d_in[11];
    const float* wW   = (const float*)d_in[12];
    const float* wb   = (const float*)d_in[13];
    const float* pos  = (const float*)d_in[14];
    const float* Wq = (const float*)d_in[15];
    const float* Wk = (const float*)d_in[16];
    const float* Wv = (const float*)d_in[17];
    const float* bq = (const float*)d_in[18];
    const float* bk = (const float*)d_in[19];
    const float* bv = (const float*)d_in[20];
    const float* Wo = (const float*)d_in[21];
    const float* bo = (const float*)d_in[22];
    const float* ln1_g = (const float*)d_in[23];
    const float* ln1_b = (const float*)d_in[24];
    const float* f_W1 = (const float*)d_in[25];
    const float* f_b1 = (const float*)d_in[26];
    const float* f_W2 = (const float*)d_in[27];
    const float* f_b2 = (const float*)d_in[28];
    const float* ln2_g = (const float*)d_in[29];
    const float* ln2_b = (const float*)d_in[30];
    const float* Vmat = (const float*)d_in[31];
    const float* bias = (const float*)d_in[32];

    const int E   = in_sizes[1];
    const int NTt = in_sizes[3];
    const int nNodes = in_sizes[6] / D_DIM;
    const int nb = (nNodes + SCAN_CHUNK - 1) / SCAN_CHUNK;

    char* ws = (char*)d_ws;
    size_t off = 0;
    auto alloc = [&](size_t bytes) -> char* {
        char* p = ws + off;
        off = (off + bytes + 255) & ~(size_t)255;
        return p;
    };
    // zero-initialized region first
    unsigned* cnt_i = (unsigned*)alloc((size_t)nNodes * 4);
    float*    Xkseg = (float*)alloc(128 * 64 * 4);
    unsigned* cntw  = (unsigned*)alloc(512);
    size_t zeroBytes = off;
    // rest (written before read)
    unsigned* bsum   = (unsigned*)alloc(512 * 4);
    unsigned* boff   = (unsigned*)alloc(512 * 4);
    unsigned* offs   = (unsigned*)alloc((size_t)(nNodes + 1) * 4);
    unsigned* cursor = (unsigned*)alloc((size_t)nNodes * 4);
    int2*     sorted_ek = (int2*)alloc((size_t)E * 8);
    unsigned char* Nmat8 = (unsigned char*)alloc((size_t)nNodes * 128);
    float* Xi = (float*)alloc((size_t)nNodes * 64 * 4);
    float* cntraw = (float*)alloc((size_t)nNodes * 4);
    float* invcnt = (float*)alloc((size_t)nNodes * 4);
    float* U1 = (float*)alloc((size_t)nNodes * 128 * 4);
    float* U2 = (float*)alloc((size_t)nNodes * 128 * 4);
    float* partials = (float*)alloc((size_t)WB_BLOCKS * 16384 * 4);
    unsigned short* Bt0 = (unsigned short*)alloc(128 * 320 * 2);
    unsigned short* Bt1 = (unsigned short*)alloc(128 * 320 * 2);
    float* Wmsg0 = (float*)alloc(65536);
    float* Wmsg1 = (float*)alloc(65536);
    float* W1 = (float*)alloc(65536);
    float* W2 = (float*)alloc(65536);
    float* P2_0 = (float*)alloc(65536);
    float* P2_1 = (float*)alloc(65536);
    float* P3_0 = (float*)alloc(32768);
    float* P3_1 = (float*)alloc(32768);
    float* ebx0 = (float*)alloc(512);
    float* ebx1 = (float*)alloc(512);
    float* Wmsgn0 = (float*)alloc(65536);
    float* Wmsgn1 = (float*)alloc(65536);
    float* Xmat  = (float*)alloc(65536);
    float* qm    = (float*)alloc(65536);
    float* km    = (float*)alloc(65536);
    float* vm    = (float*)alloc(65536);
    float* attnO = (float*)alloc(65536);
    float* pre1  = (float*)alloc(65536);
    float* H1m   = (float*)alloc(65536);
    float* F1    = (float*)alloc(262144);
    float* pre2  = (float*)alloc(65536);
    float* Wfm   = (float*)alloc(65536);

    const float* uWt0 = uW;
    const float* uWb0 = uW + 128 * 128;
    const float* uWt1 = uW + 256 * 128;
    const float* uWb1 = uW + 256 * 128 + 128 * 128;
    const float* wWt0 = wW;
    const float* wWb0 = wW + 128 * 128;
    const float* wWt1 = wW + 256 * 128;
    const float* wWb1 = wW + 256 * 128 + 128 * 128;

    hipMemsetAsync(d_ws, 0, zeroBytes, stream);

    // ---- sorted edge pipeline ----
    hist_kernel<<<(E + 255) / 256, 256, 0, stream>>>(edge_i, edge_k, cnt_i, cntw, E);
    scan1_kernel<<<nb, 256, 0, stream>>>(cnt_i, bsum, nNodes);
    scan2_kernel<<<1, 64, 0, stream>>>(bsum, boff, offs, nb, nNodes);
    scan3_kernel<<<nb, 256, 0, stream>>>(cnt_i, boff, offs, cursor, nNodes);
    scatter_kernel<<<(E + 255) / 256, 256, 0, stream>>>(edge_i, edge_k, cursor, sorted_ek, E);
    const int BUILD_BLOCKS = 1024;
    int npw = (nNodes + BUILD_BLOCKS * 4 - 1) / (BUILD_BLOCKS * 4);
    build_kernel<<<BUILD_BLOCKS, 256, 0, stream>>>(edge_x, sorted_ek, offs,
                                                   Xi, Nmat8, cntraw, invcnt, Xkseg, nNodes, npw);

    int npb = (nNodes + WB_BLOCKS - 1) / WB_BLOCKS;
    int la_grid = (nNodes + 127) / 128;

    // ---- layer 0 ----
    gemm_kernel<<<64, 256, 0, stream>>>(w0, uWb0, nullptr, nullptr, nullptr, nullptr, P2_0, 128, 128, 128, 0, 0);
    gemm_kernel<<<32, 256, 0, stream>>>(ep_W, uWb0, nullptr, nullptr, nullptr, nullptr, P3_0, 64, 128, 128, 0, 0);
    gemm_kernel<<<1, 256, 0, stream>>>(ep_b, uWb0, nullptr, nullptr, nullptr, nullptr, ebx0, 1, 128, 128, 0, 0);
    btprep_kernel<<<160, 256, 0, stream>>>(uWt0, P2_0, P3_0, Bt0);
    wmsgB_mfma<<<WB_BLOCKS, 256, 0, stream>>>(u0, Nmat8, partials, npb, nNodes);
    reduceP_kernel<<<64, 256, 0, stream>>>(partials, Wmsg0);
    layerA_mfma<<<la_grid, 256, 0, stream>>>(u0, Nmat8, Xi, cntraw, invcnt, Bt0, ub, ebx0, U1, nNodes);
    wmsg_fin_kernel<<<64, 256, 0, stream>>>(Wmsg0, Xkseg, cntw, ep_W, ep_b, Wmsgn0);
    gemm_kernel<<<64, 256, 0, stream>>>(w0, wWt0, Wmsgn0, wWb0, wb, nullptr, W1, 128, 128, 128, 128, 1);

    // ---- layer 1 ----
    gemm_kernel<<<64, 256, 0, stream>>>(W1, uWb1, nullptr, nullptr, nullptr, nullptr, P2_1, 128, 128, 128, 0, 0);
    gemm_kernel<<<32, 256, 0, stream>>>(ep_W, uWb1, nullptr, nullptr, nullptr, nullptr, P3_1, 64, 128, 128, 0, 0);
    gemm_kernel<<<1, 256, 0, stream>>>(ep_b, uWb1, nullptr, nullptr, nullptr, nullptr, ebx1, 1, 128, 128, 0, 0);
    btprep_kernel<<<160, 256, 0, stream>>>(uWt1, P2_1, P3_1, Bt1);
    wmsgB_mfma<<<WB_BLOCKS, 256, 0, stream>>>(U1, Nmat8, partials, npb, nNodes);
    reduceP_kernel<<<64, 256, 0, stream>>>(partials, Wmsg1);
    layerA_mfma<<<la_grid, 256, 0, stream>>>(U1, Nmat8, Xi, cntraw, invcnt, Bt1, ub + 128, ebx1, U2, nNodes);
    wmsg_fin_kernel<<<64, 256, 0, stream>>>(Wmsg1, Xkseg, cntw, ep_W, ep_b, Wmsgn1);
    gemm_kernel<<<64, 256, 0, stream>>>(W1, wWt1, Wmsgn1, wWb1, wb + 128, nullptr, W2, 128, 128, 128, 128, 1);

    // ---- TimeRefine ----
    add_kernel<<<64, 256, 0, stream>>>(W2, pos, Xmat, 128 * 128);
    gemm_kernel<<<64, 256, 0, stream>>>(Xmat, Wq, nullptr, nullptr, bq, nullptr, qm, 128, 128, 128, 0, 0);
    gemm_kernel<<<64, 256, 0, stream>>>(Xmat, Wk, nullptr, nullptr, bk, nullptr, km, 128, 128, 128, 0, 0);
    gemm_kernel<<<64, 256, 0, stream>>>(Xmat, Wv, nullptr, nullptr, bv, nullptr, vm, 128, 128, 128, 0, 0);
    attn_kernel<<<128, 128, 0, stream>>>(qm, km, vm, attnO);
    gemm_kernel<<<64, 256, 0, stream>>>(attnO, Wo, nullptr, nullptr, bo, Xmat, pre1, 128, 128, 128, 0, 0);
    ln_kernel<<<128, 128, 0, stream>>>(pre1, ln1_g, ln1_b, H1m);
    gemm_kernel<<<256, 256, 0, stream>>>(H1m, f_W1, nullptr, nullptr, f_b1, nullptr, F1, 128, 512, 128, 0, 1);
    gemm_kernel<<<64, 256, 0, stream>>>(F1, f_W2, nullptr, nullptr, f_b2, H1m, pre2, 128, 128, 512, 0, 0);
    ln_kernel<<<128, 128, 0, stream>>>(pre2, ln2_g, ln2_b, Wfm);

    // ---- decode ----
    decode_kernel<<<(NTt + 15) / 16, 256, 0, stream>>>(idx_i, idx_j, idx_k, U2, Wfm, Vmat,
                                                       bias, (float*)d_out, NTt);
}

// Round 5
// 1459.775 us; speedup vs baseline: 2.0066x; 1.3014x over previous
//
#include <hip/hip_runtime.h>
#include <hip/hip_bf16.h>

#define D_DIM 128
#define KT 128
#define JF 64
#define WB_BLOCKS 256

typedef __attribute__((ext_vector_type(8))) short bf16x8;
typedef __attribute__((ext_vector_type(4))) float f32x4;

__device__ inline unsigned short f2b(float f) {
    __hip_bfloat16 h = __float2bfloat16(f);
    return *reinterpret_cast<unsigned short*>(&h);
}

// ---------------------------------------------------------------------------
// edge_pass: wave per edge. Xi += edge_x row (global f32 atomics),
// Nmat32[i][k]++ (global u32 atomic), Xk/cntw LDS-privatized.
// ~1M random 256B segments -> ~2.6 G seg/s wall -> ~380 us.
// ---------------------------------------------------------------------------
__global__ void __launch_bounds__(256) edge_pass_kernel(
    const float* __restrict__ edge_x, const int* __restrict__ edge_i,
    const int* __restrict__ edge_k, float* __restrict__ Xi, float* __restrict__ Xk,
    unsigned* __restrict__ Nmat32, unsigned* __restrict__ cntw, int E, int epb)
{
    __shared__ float xk_s[KT * JF];      // 32 KB
    __shared__ unsigned cw_s[KT];
    for (int t = threadIdx.x; t < KT * JF; t += 256) xk_s[t] = 0.f;
    if (threadIdx.x < KT) cw_s[threadIdx.x] = 0u;
    __syncthreads();
    const int wid = threadIdx.x >> 6, lane = threadIdx.x & 63;
    const long base = (long)blockIdx.x * epb;
    for (int c = wid; c < epb; c += 4) {
        long e = base + c;
        if (e >= (long)E) break;
        int i = edge_i[e], k = edge_k[e];
        float x = edge_x[e * 64 + lane];
        unsafeAtomicAdd(&Xi[(long)i * 64 + lane], x);
        unsafeAtomicAdd(&xk_s[k * 64 + lane], x);
        if (lane == 0) atomicAdd(&Nmat32[(long)i * 128 + k], 1u);
        if (lane == 1) atomicAdd(&cw_s[k], 1u);
    }
    __syncthreads();
    for (int t = threadIdx.x; t < KT * JF; t += 256) {
        float v = xk_s[t];
        if (v != 0.f) unsafeAtomicAdd(&Xk[t], v);
    }
    if (threadIdx.x < KT && cw_s[threadIdx.x]) atomicAdd(&cntw[threadIdx.x], cw_s[threadIdx.x]);
}

// cnt: per-row sum of Nmat32 -> cntraw/invcnt; convert to u8 Nmat8.
__global__ void __launch_bounds__(256) cnt_kernel(
    const unsigned* __restrict__ Nmat32, unsigned char* __restrict__ Nmat8,
    float* __restrict__ cntraw, float* __restrict__ invcnt, int nNodes)
{
    int row = blockIdx.x * 4 + (threadIdx.x >> 6);
    int lane = threadIdx.x & 63;
    if (row >= nNodes) return;
    uint2 v = *(const uint2*)&Nmat32[(long)row * 128 + lane * 2];
    unsigned s = v.x + v.y;
    #pragma unroll
    for (int o = 32; o; o >>= 1) s += __shfl_down(s, o, 64);
    unsigned char c0 = (unsigned char)v.x, c1 = (unsigned char)v.y;
    uchar2 o2; o2.x = c0; o2.y = c1;
    *(uchar2*)&Nmat8[(long)row * 128 + lane * 2] = o2;
    if (lane == 0) {
        float c = (float)s;
        cntraw[row] = c;
        invcnt[row] = 1.f / fmaxf(c, 1.f);
    }
}

// ---------------------------------------------------------------------------
// prep: fused P2/P3/ebx/btprep. Bt[n][kk] (bf16, stride 320):
//   kk<128: uWt[kk][n]; 128..255: (Wl@uWb)[kk-128][n]; 256..319: (ep_W@uWb)[kk-256][n]
// plus ebx[n] = ep_b@uWb.
// ---------------------------------------------------------------------------
__global__ void prep_kernel(const float* __restrict__ uWt, const float* __restrict__ Wl,
                            const float* __restrict__ uWb, const float* __restrict__ ep_W,
                            const float* __restrict__ ep_b,
                            unsigned short* __restrict__ Bt, float* __restrict__ ebx)
{
    int idx = blockIdx.x * 256 + threadIdx.x;
    if (idx < 128 * 320) {
        int n = idx / 320, kk = idx - n * 320;
        float v;
        if (kk < 128) {
            v = uWt[kk * 128 + n];
        } else {
            const float* a = (kk < 256) ? (Wl + (kk - 128) * 128) : (ep_W + (kk - 256) * 128);
            float s = 0.f;
            #pragma unroll 8
            for (int j = 0; j < 128; ++j) s += a[j] * uWb[j * 128 + n];
            v = s;
        }
        Bt[idx] = f2b(v);
    } else if (idx < 128 * 320 + 128) {
        int n = idx - 128 * 320;
        float s = 0.f;
        #pragma unroll 8
        for (int j = 0; j < 128; ++j) s += ep_b[j] * uWb[j * 128 + n];
        ebx[n] = s;
    }
}

// ---------------------------------------------------------------------------
// layerA MFMA: U_out[128-node tile] = relu(A[128x320]@B[320x128] + ub + flag*ebx)
// ---------------------------------------------------------------------------
__global__ void __launch_bounds__(256) layerA_mfma(
    const float* __restrict__ U_in, const unsigned char* __restrict__ Nmat8,
    const float* __restrict__ Xi, const float* __restrict__ cntraw,
    const float* __restrict__ invcnt, const unsigned short* __restrict__ Bt,
    const float* __restrict__ ub_l, const float* __restrict__ ebx,
    float* __restrict__ U_out, int nNodes)
{
    __shared__ __align__(16) unsigned short A_s[128][40];
    __shared__ __align__(16) unsigned short B_s[128][40];
    const int tid = threadIdx.x;
    const int w = tid >> 6, lane = tid & 63;
    const int quad = lane >> 4, l16 = lane & 15;
    const int nodeBase = blockIdx.x * 128;
    f32x4 acc[2][8];
    #pragma unroll
    for (int a = 0; a < 2; ++a)
        #pragma unroll
        for (int b = 0; b < 8; ++b) acc[a][b] = (f32x4){0.f, 0.f, 0.f, 0.f};

    const int rr = tid >> 3;          // 0..31
    const int kc = (tid & 7) * 4;     // 0..28

    for (int ks = 0; ks < 10; ++ks) {
        const int k0 = ks * 32;
        __syncthreads();
        {
            int n = tid & 127, seg = tid >> 7;
            const unsigned short* src = Bt + n * 320 + k0 + seg * 16;
            uint4 p0 = *(const uint4*)(src);
            uint4 p1 = *(const uint4*)(src + 8);
            *(uint4*)&B_s[n][seg * 16]     = p0;
            *(uint4*)&B_s[n][seg * 16 + 8] = p1;
        }
        #pragma unroll
        for (int p = 0; p < 4; ++p) {
            int r = p * 32 + rr;
            int node = nodeBase + r;
            float4 v = {0.f, 0.f, 0.f, 0.f};
            if (node < nNodes) {
                if (ks < 4) {
                    v = *(const float4*)&U_in[(long)node * 128 + k0 + kc];
                } else if (ks < 8) {
                    float inv = invcnt[node];
                    const unsigned char* np_ = &Nmat8[(long)node * 128 + (k0 - 128) + kc];
                    v.x = (float)np_[0] * inv; v.y = (float)np_[1] * inv;
                    v.z = (float)np_[2] * inv; v.w = (float)np_[3] * inv;
                } else {
                    float inv = invcnt[node];
                    float4 x = *(const float4*)&Xi[(long)node * 64 + (k0 - 256) + kc];
                    v.x = x.x * inv; v.y = x.y * inv; v.z = x.z * inv; v.w = x.w * inv;
                }
            }
            ushort4 w4 = make_ushort4(f2b(v.x), f2b(v.y), f2b(v.z), f2b(v.w));
            *(ushort4*)&A_s[r][kc] = w4;
        }
        __syncthreads();
        bf16x8 a0 = *(const bf16x8*)&A_s[w * 32 + l16][quad * 8];
        bf16x8 a1 = *(const bf16x8*)&A_s[w * 32 + 16 + l16][quad * 8];
        #pragma unroll
        for (int nt = 0; nt < 8; ++nt) {
            bf16x8 b = *(const bf16x8*)&B_s[nt * 16 + l16][quad * 8];
            acc[0][nt] = __builtin_amdgcn_mfma_f32_16x16x32_bf16(a0, b, acc[0][nt], 0, 0, 0);
            acc[1][nt] = __builtin_amdgcn_mfma_f32_16x16x32_bf16(a1, b, acc[1][nt], 0, 0, 0);
        }
    }
    #pragma unroll
    for (int mt = 0; mt < 2; ++mt) {
        #pragma unroll
        for (int r = 0; r < 4; ++r) {
            int row = w * 32 + mt * 16 + quad * 4 + r;
            int node = nodeBase + row;
            if (node < nNodes) {
                float flag = (cntraw[node] > 0.f) ? 1.f : 0.f;
                #pragma unroll
                for (int nt = 0; nt < 8; ++nt) {
                    int col = nt * 16 + l16;
                    float vv = acc[mt][nt][r] + ub_l[col] + flag * ebx[col];
                    U_out[(long)node * 128 + col] = fmaxf(vv, 0.f);
                }
            }
        }
    }
}

// ---------------------------------------------------------------------------
// wmsgB MFMA: partial[b] = N^T_chunk @ U_chunk
// ---------------------------------------------------------------------------
__global__ void __launch_bounds__(256) wmsgB_mfma(
    const float* __restrict__ U, const unsigned char* __restrict__ Nmat8,
    float* __restrict__ partial, int nodes_per_block, int nNodes)
{
    __shared__ __align__(16) unsigned short A_s[128][40];  // [ktok][node]
    __shared__ __align__(16) unsigned short B_s[128][40];  // [d][node]
    const int tid = threadIdx.x;
    const int w = tid >> 6, lane = tid & 63;
    const int quad = lane >> 4, l16 = lane & 15;
    f32x4 acc[2][8];
    #pragma unroll
    for (int a = 0; a < 2; ++a)
        #pragma unroll
        for (int b = 0; b < 8; ++b) acc[a][b] = (f32x4){0.f, 0.f, 0.f, 0.f};

    int base = blockIdx.x * nodes_per_block;
    int end = min(base + nodes_per_block, nNodes);
    const int nn = tid >> 3;          // 0..31
    const int cc = (tid & 7) * 16;    // 0..112
    for (int g = base; g < end; g += 32) {
        int cnt = min(32, end - g);
        __syncthreads();
        if (nn < cnt) {
            int node = g + nn;
            uint4 nb = *(const uint4*)&Nmat8[(long)node * 128 + cc];
            const unsigned char* nbp = (const unsigned char*)&nb;
            float4 u4[4];
            #pragma unroll
            for (int q = 0; q < 4; ++q)
                u4[q] = *(const float4*)&U[(long)node * 128 + cc + q * 4];
            const float* up = (const float*)u4;
            #pragma unroll
            for (int j = 0; j < 16; ++j) {
                A_s[cc + j][nn] = f2b((float)nbp[j]);
                B_s[cc + j][nn] = f2b(up[j]);
            }
        } else {
            #pragma unroll
            for (int j = 0; j < 16; ++j) { A_s[cc + j][nn] = 0; B_s[cc + j][nn] = 0; }
        }
        __syncthreads();
        bf16x8 a0 = *(const bf16x8*)&A_s[w * 32 + l16][quad * 8];
        bf16x8 a1 = *(const bf16x8*)&A_s[w * 32 + 16 + l16][quad * 8];
        #pragma unroll
        for (int nt = 0; nt < 8; ++nt) {
            bf16x8 b = *(const bf16x8*)&B_s[nt * 16 + l16][quad * 8];
            acc[0][nt] = __builtin_amdgcn_mfma_f32_16x16x32_bf16(a0, b, acc[0][nt], 0, 0, 0);
            acc[1][nt] = __builtin_amdgcn_mfma_f32_16x16x32_bf16(a1, b, acc[1][nt], 0, 0, 0);
        }
    }
    float* my = partial + (size_t)blockIdx.x * 16384;
    #pragma unroll
    for (int mt = 0; mt < 2; ++mt)
        #pragma unroll
        for (int r = 0; r < 4; ++r) {
            int row = w * 32 + mt * 16 + quad * 4 + r;
            #pragma unroll
            for (int nt = 0; nt < 8; ++nt)
                my[row * 128 + nt * 16 + l16] = acc[mt][nt][r];
        }
}

__global__ void reduceP_kernel(const float* __restrict__ partial, float* __restrict__ Wmsg)
{
    int idx = blockIdx.x * 256 + threadIdx.x;
    float s = 0.f;
    #pragma unroll 4
    for (int b = 0; b < WB_BLOCKS; ++b) s += partial[(size_t)b * 16384 + idx];
    Wmsg[idx] = s;
}

__global__ void wmsg_fin_kernel(const float* __restrict__ Wmsg, const float* __restrict__ Xk,
                                const unsigned* __restrict__ cntw, const float* __restrict__ ep_W,
                                const float* __restrict__ ep_b, float* __restrict__ out)
{
    int idx = blockIdx.x * 256 + threadIdx.x;
    int kk = idx >> 7, d = idx & 127;
    float s = Wmsg[idx];
    const float* xk = Xk + kk * 64;
    #pragma unroll 8
    for (int j = 0; j < 64; ++j) s += xk[j] * ep_W[j * 128 + d];
    float c = (float)cntw[kk];
    s += c * ep_b[d];
    out[idx] = s / fmaxf(c, 1.f);
}

__global__ void gemm_kernel(const float* __restrict__ A, const float* __restrict__ B,
                            const float* __restrict__ A2, const float* __restrict__ B2,
                            const float* __restrict__ bias, const float* __restrict__ res,
                            float* __restrict__ C, int M, int N, int K, int K2, int act)
{
    int idx = blockIdx.x * 256 + threadIdx.x;
    if (idx >= M * N) return;
    int m = idx / N, n = idx - m * N;
    float s = bias ? bias[n] : 0.f;
    const float* a = A + (long)m * K;
    for (int k = 0; k < K; ++k) s += a[k] * B[(long)k * N + n];
    if (A2) {
        const float* a2 = A2 + (long)m * K2;
        for (int k = 0; k < K2; ++k) s += a2[k] * B2[(long)k * N + n];
    }
    if (res) s += res[idx];
    if (act) s = fmaxf(s, 0.f);
    C[idx] = s;
}

__global__ void add_kernel(const float* __restrict__ A, const float* __restrict__ B,
                           float* __restrict__ C, int n)
{
    int i = blockIdx.x * 256 + threadIdx.x;
    if (i < n) C[i] = A[i] + B[i];
}

// fused Q/K/V projection: 128 tokens x 384 outputs
__global__ void qkv_kernel(const float* __restrict__ X,
                           const float* __restrict__ Wq, const float* __restrict__ Wk,
                           const float* __restrict__ Wv, const float* __restrict__ bq,
                           const float* __restrict__ bk, const float* __restrict__ bv,
                           float* __restrict__ qm, float* __restrict__ km, float* __restrict__ vm)
{
    int idx = blockIdx.x * 256 + threadIdx.x;
    if (idx >= 128 * 384) return;
    int m = idx / 384, c = idx - m * 384;
    int sel = c >> 7, n = c & 127;
    const float* W = (sel == 0) ? Wq : (sel == 1) ? Wk : Wv;
    const float* b = (sel == 0) ? bq : (sel == 1) ? bk : bv;
    float s = b[n];
    const float* x = X + m * 128;
    #pragma unroll 8
    for (int k = 0; k < 128; ++k) s += x[k] * W[k * 128 + n];
    float* o = (sel == 0) ? qm : (sel == 1) ? km : vm;
    o[m * 128 + n] = s;
}

__global__ void attn_kernel(const float* __restrict__ q, const float* __restrict__ kmat,
                            const float* __restrict__ vmat, float* __restrict__ outp)
{
    __shared__ float p_s[128];
    __shared__ float red_s[4];
    const int tok = blockIdx.x;
    const int t = threadIdx.x;
    const int lane = t & 63, wid = t >> 6;
    for (int h = 0; h < 2; ++h) {
        const float* qr = q + tok * 128 + h * 64;
        const float* kr = kmat + t * 128 + h * 64;
        float s = 0.f;
        #pragma unroll
        for (int d = 0; d < 64; ++d) s += qr[d] * kr[d];
        s *= 0.125f;
        float m = s;
        #pragma unroll
        for (int o = 32; o; o >>= 1) m = fmaxf(m, __shfl_down(m, o, 64));
        if (lane == 0) red_s[wid] = m;
        __syncthreads();
        m = fmaxf(red_s[0], red_s[1]);
        float ev = expf(s - m);
        float ss = ev;
        #pragma unroll
        for (int o = 32; o; o >>= 1) ss += __shfl_down(ss, o, 64);
        if (lane == 0) red_s[2 + wid] = ss;
        __syncthreads();
        float tot = red_s[2] + red_s[3];
        p_s[t] = ev / tot;
        __syncthreads();
        if (t < 64) {
            float o = 0.f;
            #pragma unroll 8
            for (int j = 0; j < 128; ++j) o += p_s[j] * vmat[j * 128 + h * 64 + t];
            outp[tok * 128 + h * 64 + t] = o;
        }
        __syncthreads();
    }
}

__global__ void ln_kernel(const float* __restrict__ x, const float* __restrict__ g,
                          const float* __restrict__ b, float* __restrict__ y)
{
    __shared__ float red_s[4];
    const int row = blockIdx.x, t = threadIdx.x, lane = t & 63, wid = t >> 6;
    float v = x[row * 128 + t];
    float s = v;
    #pragma unroll
    for (int o = 32; o; o >>= 1) s += __shfl_down(s, o, 64);
    if (lane == 0) red_s[wid] = s;
    __syncthreads();
    float mean = (red_s[0] + red_s[1]) * (1.f / 128.f);
    float d = v - mean;
    float q2 = d * d;
    #pragma unroll
    for (int o = 32; o; o >>= 1) q2 += __shfl_down(q2, o, 64);
    if (lane == 0) red_s[2 + wid] = q2;
    __syncthreads();
    float var = (red_s[2] + red_s[3]) * (1.f / 128.f);
    y[row * 128 + t] = d * rsqrtf(var + 1e-5f) * g[t] + b[t];
}

// decode: 16 lanes per triple (4 triples/wave), float4 pairs, width-16 reduce
__global__ void __launch_bounds__(256) decode_kernel(
    const int* __restrict__ idx_i, const int* __restrict__ idx_j, const int* __restrict__ idx_k,
    const float* __restrict__ U2, const float* __restrict__ Wf, const float* __restrict__ V,
    const float* __restrict__ bias, float* __restrict__ out, int n)
{
    const int g = threadIdx.x >> 4;      // 0..15
    const int hl = threadIdx.x & 15;
    int t = blockIdx.x * 16 + g;
    if (t >= n) return;
    int i = idx_i[t], j = idx_j[t], kk = idx_k[t];
    const float* up = U2 + (long)i * 128 + hl * 8;
    const float* wp = Wf + kk * 128 + hl * 8;
    const float* vp = V + j * 128 + hl * 8;
    float4 u0 = *(const float4*)up,       u1 = *(const float4*)(up + 4);
    float4 w0 = *(const float4*)wp,       w1 = *(const float4*)(wp + 4);
    float4 v0 = *(const float4*)vp,       v1 = *(const float4*)(vp + 4);
    float s = u0.x * w0.x * v0.x + u0.y * w0.y * v0.y + u0.z * w0.z * v0.z + u0.w * w0.w * v0.w
            + u1.x * w1.x * v1.x + u1.y * w1.y * v1.y + u1.z * w1.z * v1.z + u1.w * w1.w * v1.w;
    #pragma unroll
    for (int o = 8; o; o >>= 1) s += __shfl_down(s, o, 16);
    if (hl == 0) out[t] = 1.f / (1.f + expf(-(s + bias[0])));
}

// ---------------------------------------------------------------------------
extern "C" void kernel_launch(void* const* d_in, const int* in_sizes, int n_in,
                              void* d_out, int out_size, void* d_ws, size_t ws_size,
                              hipStream_t stream)
{
    const float* edge_x = (const float*)d_in[0];
    const int*   edge_i = (const int*)d_in[1];
    const int*   edge_k = (const int*)d_in[2];
    const int*   idx_i  = (const int*)d_in[3];
    const int*   idx_j  = (const int*)d_in[4];
    const int*   idx_k  = (const int*)d_in[5];
    const float* u0   = (const float*)d_in[6];
    const float* w0   = (const float*)d_in[7];
    const float* ep_W = (const float*)d_in[8];
    const float* ep_b = (const float*)d_in[9];
    const float* uW   = (const float*)d_in[10];
    const float* ub   = (const float*)d_in[11];
    const float* wW   = (const float*)d_in[12];
    const float* wb   = (const float*)d_in[13];
    const float* pos  = (const float*)d_in[14];
    const float* Wq = (const float*)d_in[15];
    const float* Wk = (const float*)d_in[16];
    const float* Wv = (const float*)d_in[17];
    const float* bq = (const float*)d_in[18];
    const float* bk = (const float*)d_in[19];
    const float* bv = (const float*)d_in[20];
    const float* Wo = (const float*)d_in[21];
    const float* bo = (const float*)d_in[22];
    const float* ln1_g = (const float*)d_in[23];
    const float* ln1_b = (const float*)d_in[24];
    const float* f_W1 = (const float*)d_in[25];
    const float* f_b1 = (const float*)d_in[26];
    const float* f_W2 = (const float*)d_in[27];
    const float* f_b2 = (const float*)d_in[28];
    const float* ln2_g = (const float*)d_in[29];
    const float* ln2_b = (const float*)d_in[30];
    const float* Vmat = (const float*)d_in[31];
    const float* bias = (const float*)d_in[32];

    const int E   = in_sizes[1];
    const int NTt = in_sizes[3];
    const int nNodes = in_sizes[6] / D_DIM;

    char* ws = (char*)d_ws;
    size_t off = 0;
    auto alloc = [&](size_t bytes) -> char* {
        char* p = ws + off;
        off = (off + bytes + 255) & ~(size_t)255;
        return p;
    };
    // zero-initialized region first (single memset)
    unsigned* Nmat32 = (unsigned*)alloc((size_t)nNodes * 128 * 4);
    float*    Xi     = (float*)alloc((size_t)nNodes * 64 * 4);
    float*    Xkseg  = (float*)alloc(128 * 64 * 4);
    unsigned* cntw   = (unsigned*)alloc(512);
    size_t zeroBytes = off;
    // rest (written before read)
    unsigned char* Nmat8 = (unsigned char*)alloc((size_t)nNodes * 128);
    float* cntraw = (float*)alloc((size_t)nNodes * 4);
    float* invcnt = (float*)alloc((size_t)nNodes * 4);
    float* U1 = (float*)alloc((size_t)nNodes * 128 * 4);
    float* U2 = (float*)alloc((size_t)nNodes * 128 * 4);
    float* partials = (float*)alloc((size_t)WB_BLOCKS * 16384 * 4);
    unsigned short* Bt0 = (unsigned short*)alloc(128 * 320 * 2);
    unsigned short* Bt1 = (unsigned short*)alloc(128 * 320 * 2);
    float* Wmsg0 = (float*)alloc(65536);
    float* Wmsg1 = (float*)alloc(65536);
    float* W1 = (float*)alloc(65536);
    float* W2 = (float*)alloc(65536);
    float* ebx0 = (float*)alloc(512);
    float* ebx1 = (float*)alloc(512);
    float* Wmsgn0 = (float*)alloc(65536);
    float* Wmsgn1 = (float*)alloc(65536);
    float* Xmat  = (float*)alloc(65536);
    float* qm    = (float*)alloc(65536);
    float* km    = (float*)alloc(65536);
    float* vm    = (float*)alloc(65536);
    float* attnO = (float*)alloc(65536);
    float* pre1  = (float*)alloc(65536);
    float* H1m   = (float*)alloc(65536);
    float* F1    = (float*)alloc(262144);
    float* pre2  = (float*)alloc(65536);
    float* Wfm   = (float*)alloc(65536);

    const float* uWt0 = uW;
    const float* uWb0 = uW + 128 * 128;
    const float* uWt1 = uW + 256 * 128;
    const float* uWb1 = uW + 256 * 128 + 128 * 128;
    const float* wWt0 = wW;
    const float* wWb0 = wW + 128 * 128;
    const float* wWt1 = wW + 256 * 128;
    const float* wWb1 = wW + 256 * 128 + 128 * 128;

    hipMemsetAsync(d_ws, 0, zeroBytes, stream);

    // ---- edge pass (direct atomics; ~2.6 G random-segment/s wall) ----
    int epb = (E + 1023) / 1024;
    edge_pass_kernel<<<1024, 256, 0, stream>>>(edge_x, edge_i, edge_k, Xi, Xkseg,
                                               Nmat32, cntw, E, epb);
    cnt_kernel<<<(nNodes + 3) / 4, 256, 0, stream>>>(Nmat32, Nmat8, cntraw, invcnt, nNodes);

    int npb = (nNodes + WB_BLOCKS - 1) / WB_BLOCKS;
    int la_grid = (nNodes + 127) / 128;

    // ---- layer 0 ----
    prep_kernel<<<161, 256, 0, stream>>>(uWt0, w0, uWb0, ep_W, ep_b, Bt0, ebx0);
    wmsgB_mfma<<<WB_BLOCKS, 256, 0, stream>>>(u0, Nmat8, partials, npb, nNodes);
    reduceP_kernel<<<64, 256, 0, stream>>>(partials, Wmsg0);
    layerA_mfma<<<la_grid, 256, 0, stream>>>(u0, Nmat8, Xi, cntraw, invcnt, Bt0, ub, ebx0, U1, nNodes);
    wmsg_fin_kernel<<<64, 256, 0, stream>>>(Wmsg0, Xkseg, cntw, ep_W, ep_b, Wmsgn0);
    gemm_kernel<<<64, 256, 0, stream>>>(w0, wWt0, Wmsgn0, wWb0, wb, nullptr, W1, 128, 128, 128, 128, 1);

    // ---- layer 1 ----
    prep_kernel<<<161, 256, 0, stream>>>(uWt1, W1, uWb1, ep_W, ep_b, Bt1, ebx1);
    wmsgB_mfma<<<WB_BLOCKS, 256, 0, stream>>>(U1, Nmat8, partials, npb, nNodes);
    reduceP_kernel<<<64, 256, 0, stream>>>(partials, Wmsg1);
    layerA_mfma<<<la_grid, 256, 0, stream>>>(U1, Nmat8, Xi, cntraw, invcnt, Bt1, ub + 128, ebx1, U2, nNodes);
    wmsg_fin_kernel<<<64, 256, 0, stream>>>(Wmsg1, Xkseg, cntw, ep_W, ep_b, Wmsgn1);
    gemm_kernel<<<64, 256, 0, stream>>>(W1, wWt1, Wmsgn1, wWb1, wb + 128, nullptr, W2, 128, 128, 128, 128, 1);

    // ---- TimeRefine ----
    add_kernel<<<64, 256, 0, stream>>>(W2, pos, Xmat, 128 * 128);
    qkv_kernel<<<192, 256, 0, stream>>>(Xmat, Wq, Wk, Wv, bq, bk, bv, qm, km, vm);
    attn_kernel<<<128, 128, 0, stream>>>(qm, km, vm, attnO);
    gemm_kernel<<<64, 256, 0, stream>>>(attnO, Wo, nullptr, nullptr, bo, Xmat, pre1, 128, 128, 128, 0, 0);
    ln_kernel<<<128, 128, 0, stream>>>(pre1, ln1_g, ln1_b, H1m);
    gemm_kernel<<<256, 256, 0, stream>>>(H1m, f_W1, nullptr, nullptr, f_b1, nullptr, F1, 128, 512, 128, 0, 1);
    gemm_kernel<<<64, 256, 0, stream>>>(F1, f_W2, nullptr, nullptr, f_b2, H1m, pre2, 128, 128, 512, 0, 0);
    ln_kernel<<<128, 128, 0, stream>>>(pre2, ln2_g, ln2_b, Wfm);

    // ---- decode ----
    decode_kernel<<<(NTt + 15) / 16, 256, 0, stream>>>(idx_i, idx_j, idx_k, U2, Wfm, Vmat,
                                                       bias, (float*)d_out, NTt);
}

// Round 6
// 1417.620 us; speedup vs baseline: 2.0662x; 1.0297x over previous
//
#include <hip/hip_runtime.h>
#include <hip/hip_bf16.h>

#define D_DIM 128
#define KT 128
#define JF 64
#define WB_BLOCKS 256

typedef __attribute__((ext_vector_type(8))) short bf16x8;
typedef __attribute__((ext_vector_type(4))) float f32x4;

__device__ inline unsigned short f2b(float f) {
    __hip_bfloat16 h = __float2bfloat16(f);
    return *reinterpret_cast<unsigned short*>(&h);
}
__device__ inline float b2f(unsigned short u) {
    unsigned int x = ((unsigned int)u) << 16;
    return __uint_as_float(x);
}

// ---------------------------------------------------------------------------
// edge_pass: wave per edge. Xi += edge_x row (global f32 atomics),
// Nmat32[i][k]++ (global u32 atomic), Xk/cntw LDS-privatized.
// ~1M random 256B segments -> ~2.6 G seg/s wall -> ~380 us (known plateau).
// ---------------------------------------------------------------------------
__global__ void __launch_bounds__(256) edge_pass_kernel(
    const float* __restrict__ edge_x, const int* __restrict__ edge_i,
    const int* __restrict__ edge_k, float* __restrict__ Xi, float* __restrict__ Xk,
    unsigned* __restrict__ Nmat32, unsigned* __restrict__ cntw, int E, int epb)
{
    __shared__ float xk_s[KT * JF];      // 32 KB
    __shared__ unsigned cw_s[KT];
    for (int t = threadIdx.x; t < KT * JF; t += 256) xk_s[t] = 0.f;
    if (threadIdx.x < KT) cw_s[threadIdx.x] = 0u;
    __syncthreads();
    const int wid = threadIdx.x >> 6, lane = threadIdx.x & 63;
    const long base = (long)blockIdx.x * epb;
    for (int c = wid; c < epb; c += 4) {
        long e = base + c;
        if (e >= (long)E) break;
        int i = edge_i[e], k = edge_k[e];
        float x = edge_x[e * 64 + lane];
        unsafeAtomicAdd(&Xi[(long)i * 64 + lane], x);
        unsafeAtomicAdd(&xk_s[k * 64 + lane], x);
        if (lane == 0) atomicAdd(&Nmat32[(long)i * 128 + k], 1u);
        if (lane == 1) atomicAdd(&cw_s[k], 1u);
    }
    __syncthreads();
    for (int t = threadIdx.x; t < KT * JF; t += 256) {
        float v = xk_s[t];
        if (v != 0.f) unsafeAtomicAdd(&Xk[t], v);
    }
    if (threadIdx.x < KT && cw_s[threadIdx.x]) atomicAdd(&cntw[threadIdx.x], cw_s[threadIdx.x]);
}

// cnt: per-row sum of Nmat32 -> cntraw/invcnt; convert to u8 Nmat8.
__global__ void __launch_bounds__(256) cnt_kernel(
    const unsigned* __restrict__ Nmat32, unsigned char* __restrict__ Nmat8,
    float* __restrict__ cntraw, float* __restrict__ invcnt, int nNodes)
{
    int row = blockIdx.x * 4 + (threadIdx.x >> 6);
    int lane = threadIdx.x & 63;
    if (row >= nNodes) return;
    uint2 v = *(const uint2*)&Nmat32[(long)row * 128 + lane * 2];
    unsigned s = v.x + v.y;
    #pragma unroll
    for (int o = 32; o; o >>= 1) s += __shfl_down(s, o, 64);
    uchar2 o2; o2.x = (unsigned char)v.x; o2.y = (unsigned char)v.y;
    *(uchar2*)&Nmat8[(long)row * 128 + lane * 2] = o2;
    if (lane == 0) {
        float c = (float)s;
        cntraw[row] = c;
        invcnt[row] = 1.f / fmaxf(c, 1.f);
    }
}

// u0cvt: fp32 -> bf16 (identical rounding to the staging that consumed fp32 before)
__global__ void __launch_bounds__(256) u0cvt_kernel(
    const float* __restrict__ in, unsigned short* __restrict__ out, long n4)
{
    long i = (long)blockIdx.x * 256 + threadIdx.x;
    long stride = (long)gridDim.x * 256;
    for (; i < n4; i += stride) {
        float4 v = *(const float4*)&in[i * 4];
        ushort4 o = make_ushort4(f2b(v.x), f2b(v.y), f2b(v.z), f2b(v.w));
        *(ushort4*)&out[i * 4] = o;
    }
}

// ---------------------------------------------------------------------------
// prep: fused P2/P3/ebx/btprep. Bt[n][kk] (bf16, stride 320)
// ---------------------------------------------------------------------------
__global__ void prep_kernel(const float* __restrict__ uWt, const float* __restrict__ Wl,
                            const float* __restrict__ uWb, const float* __restrict__ ep_W,
                            const float* __restrict__ ep_b,
                            unsigned short* __restrict__ Bt, float* __restrict__ ebx)
{
    int idx = blockIdx.x * 256 + threadIdx.x;
    if (idx < 128 * 320) {
        int n = idx / 320, kk = idx - n * 320;
        float v;
        if (kk < 128) {
            v = uWt[kk * 128 + n];
        } else {
            const float* a = (kk < 256) ? (Wl + (kk - 128) * 128) : (ep_W + (kk - 256) * 128);
            float s = 0.f;
            #pragma unroll 8
            for (int j = 0; j < 128; ++j) s += a[j] * uWb[j * 128 + n];
            v = s;
        }
        Bt[idx] = f2b(v);
    } else if (idx < 128 * 320 + 128) {
        int n = idx - 128 * 320;
        float s = 0.f;
        #pragma unroll 8
        for (int j = 0; j < 128; ++j) s += ep_b[j] * uWb[j * 128 + n];
        ebx[n] = s;
    }
}

// ---------------------------------------------------------------------------
// layerA MFMA: U_out(bf16) = relu(A[128x320]@B[320x128] + ub + flag*ebx)
// A = [U(bf16) | N*inv | Xi*inv]
// ---------------------------------------------------------------------------
__global__ void __launch_bounds__(256) layerA_mfma(
    const unsigned short* __restrict__ U_in, const unsigned char* __restrict__ Nmat8,
    const float* __restrict__ Xi, const float* __restrict__ cntraw,
    const float* __restrict__ invcnt, const unsigned short* __restrict__ Bt,
    const float* __restrict__ ub_l, const float* __restrict__ ebx,
    unsigned short* __restrict__ U_out, int nNodes)
{
    __shared__ __align__(16) unsigned short A_s[128][40];
    __shared__ __align__(16) unsigned short B_s[128][40];
    const int tid = threadIdx.x;
    const int w = tid >> 6, lane = tid & 63;
    const int quad = lane >> 4, l16 = lane & 15;
    const int nodeBase = blockIdx.x * 128;
    f32x4 acc[2][8];
    #pragma unroll
    for (int a = 0; a < 2; ++a)
        #pragma unroll
        for (int b = 0; b < 8; ++b) acc[a][b] = (f32x4){0.f, 0.f, 0.f, 0.f};

    const int rr = tid >> 3;          // 0..31
    const int kc = (tid & 7) * 4;     // 0..28

    for (int ks = 0; ks < 10; ++ks) {
        const int k0 = ks * 32;
        __syncthreads();
        {
            int n = tid & 127, seg = tid >> 7;
            const unsigned short* src = Bt + n * 320 + k0 + seg * 16;
            uint4 p0 = *(const uint4*)(src);
            uint4 p1 = *(const uint4*)(src + 8);
            *(uint4*)&B_s[n][seg * 16]     = p0;
            *(uint4*)&B_s[n][seg * 16 + 8] = p1;
        }
        #pragma unroll
        for (int p = 0; p < 4; ++p) {
            int r = p * 32 + rr;
            int node = nodeBase + r;
            ushort4 w4 = make_ushort4(0, 0, 0, 0);
            if (node < nNodes) {
                if (ks < 4) {
                    w4 = *(const ushort4*)&U_in[(long)node * 128 + k0 + kc];
                } else if (ks < 8) {
                    float inv = invcnt[node];
                    const unsigned char* np_ = &Nmat8[(long)node * 128 + (k0 - 128) + kc];
                    w4 = make_ushort4(f2b((float)np_[0] * inv), f2b((float)np_[1] * inv),
                                      f2b((float)np_[2] * inv), f2b((float)np_[3] * inv));
                } else {
                    float inv = invcnt[node];
                    float4 x = *(const float4*)&Xi[(long)node * 64 + (k0 - 256) + kc];
                    w4 = make_ushort4(f2b(x.x * inv), f2b(x.y * inv),
                                      f2b(x.z * inv), f2b(x.w * inv));
                }
            }
            *(ushort4*)&A_s[r][kc] = w4;
        }
        __syncthreads();
        bf16x8 a0 = *(const bf16x8*)&A_s[w * 32 + l16][quad * 8];
        bf16x8 a1 = *(const bf16x8*)&A_s[w * 32 + 16 + l16][quad * 8];
        #pragma unroll
        for (int nt = 0; nt < 8; ++nt) {
            bf16x8 b = *(const bf16x8*)&B_s[nt * 16 + l16][quad * 8];
            acc[0][nt] = __builtin_amdgcn_mfma_f32_16x16x32_bf16(a0, b, acc[0][nt], 0, 0, 0);
            acc[1][nt] = __builtin_amdgcn_mfma_f32_16x16x32_bf16(a1, b, acc[1][nt], 0, 0, 0);
        }
    }
    #pragma unroll
    for (int mt = 0; mt < 2; ++mt) {
        #pragma unroll
        for (int r = 0; r < 4; ++r) {
            int row = w * 32 + mt * 16 + quad * 4 + r;
            int node = nodeBase + row;
            if (node < nNodes) {
                float flag = (cntraw[node] > 0.f) ? 1.f : 0.f;
                #pragma unroll
                for (int nt = 0; nt < 8; ++nt) {
                    int col = nt * 16 + l16;
                    float vv = acc[mt][nt][r] + ub_l[col] + flag * ebx[col];
                    U_out[(long)node * 128 + col] = f2b(fmaxf(vv, 0.f));
                }
            }
        }
    }
}

// ---------------------------------------------------------------------------
// wmsgB MFMA: partial[b] = N^T_chunk @ U_chunk  (U already bf16)
// ---------------------------------------------------------------------------
__global__ void __launch_bounds__(256) wmsgB_mfma(
    const unsigned short* __restrict__ U, const unsigned char* __restrict__ Nmat8,
    float* __restrict__ partial, int nodes_per_block, int nNodes)
{
    __shared__ __align__(16) unsigned short A_s[128][40];  // [ktok][node]
    __shared__ __align__(16) unsigned short B_s[128][40];  // [d][node]
    const int tid = threadIdx.x;
    const int w = tid >> 6, lane = tid & 63;
    const int quad = lane >> 4, l16 = lane & 15;
    f32x4 acc[2][8];
    #pragma unroll
    for (int a = 0; a < 2; ++a)
        #pragma unroll
        for (int b = 0; b < 8; ++b) acc[a][b] = (f32x4){0.f, 0.f, 0.f, 0.f};

    int base = blockIdx.x * nodes_per_block;
    int end = min(base + nodes_per_block, nNodes);
    const int nn = tid >> 3;          // 0..31
    const int cc = (tid & 7) * 16;    // 0..112
    for (int g = base; g < end; g += 32) {
        int cnt = min(32, end - g);
        __syncthreads();
        if (nn < cnt) {
            int node = g + nn;
            uint4 nb = *(const uint4*)&Nmat8[(long)node * 128 + cc];
            const unsigned char* nbp = (const unsigned char*)&nb;
            uint4 ua = *(const uint4*)&U[(long)node * 128 + cc];
            uint4 ubb = *(const uint4*)&U[(long)node * 128 + cc + 8];
            unsigned short uv[16];
            *(uint4*)&uv[0] = ua;
            *(uint4*)&uv[8] = ubb;
            #pragma unroll
            for (int j = 0; j < 16; ++j) {
                A_s[cc + j][nn] = f2b((float)nbp[j]);
                B_s[cc + j][nn] = uv[j];
            }
        } else {
            #pragma unroll
            for (int j = 0; j < 16; ++j) { A_s[cc + j][nn] = 0; B_s[cc + j][nn] = 0; }
        }
        __syncthreads();
        bf16x8 a0 = *(const bf16x8*)&A_s[w * 32 + l16][quad * 8];
        bf16x8 a1 = *(const bf16x8*)&A_s[w * 32 + 16 + l16][quad * 8];
        #pragma unroll
        for (int nt = 0; nt < 8; ++nt) {
            bf16x8 b = *(const bf16x8*)&B_s[nt * 16 + l16][quad * 8];
            acc[0][nt] = __builtin_amdgcn_mfma_f32_16x16x32_bf16(a0, b, acc[0][nt], 0, 0, 0);
            acc[1][nt] = __builtin_amdgcn_mfma_f32_16x16x32_bf16(a1, b, acc[1][nt], 0, 0, 0);
        }
    }
    float* my = partial + (size_t)blockIdx.x * 16384;
    #pragma unroll
    for (int mt = 0; mt < 2; ++mt)
        #pragma unroll
        for (int r = 0; r < 4; ++r) {
            int row = w * 32 + mt * 16 + quad * 4 + r;
            #pragma unroll
            for (int nt = 0; nt < 8; ++nt)
                my[row * 128 + nt * 16 + l16] = acc[mt][nt][r];
        }
}

// reduceP: 512 blocks = 64 idx-tiles x 8 partial-groups of 32; atomic flush
// into Wmsg (zeroed by the up-front memset).
__global__ void __launch_bounds__(256) reduceP_kernel(
    const float* __restrict__ partial, float* __restrict__ Wmsg)
{
    int grp = blockIdx.x >> 6;          // 0..7
    int ib  = blockIdx.x & 63;          // 0..63
    int idx = ib * 256 + threadIdx.x;   // 0..16383
    float s = 0.f;
    #pragma unroll 8
    for (int b = 0; b < 32; ++b)
        s += partial[(size_t)(grp * 32 + b) * 16384 + idx];
    unsafeAtomicAdd(&Wmsg[idx], s);
}

__global__ void wmsg_fin_kernel(const float* __restrict__ Wmsg, const float* __restrict__ Xk,
                                const unsigned* __restrict__ cntw, const float* __restrict__ ep_W,
                                const float* __restrict__ ep_b, float* __restrict__ out)
{
    int idx = blockIdx.x * 256 + threadIdx.x;
    int kk = idx >> 7, d = idx & 127;
    float s = Wmsg[idx];
    const float* xk = Xk + kk * 64;
    #pragma unroll 8
    for (int j = 0; j < 64; ++j) s += xk[j] * ep_W[j * 128 + d];
    float c = (float)cntw[kk];
    s += c * ep_b[d];
    out[idx] = s / fmaxf(c, 1.f);
}

__global__ void gemm_kernel(const float* __restrict__ A, const float* __restrict__ B,
                            const float* __restrict__ A2, const float* __restrict__ B2,
                            const float* __restrict__ bias, const float* __restrict__ res,
                            float* __restrict__ C, int M, int N, int K, int K2, int act)
{
    int idx = blockIdx.x * 256 + threadIdx.x;
    if (idx >= M * N) return;
    int m = idx / N, n = idx - m * N;
    float s = bias ? bias[n] : 0.f;
    const float* a = A + (long)m * K;
    for (int k = 0; k < K; ++k) s += a[k] * B[(long)k * N + n];
    if (A2) {
        const float* a2 = A2 + (long)m * K2;
        for (int k = 0; k < K2; ++k) s += a2[k] * B2[(long)k * N + n];
    }
    if (res) s += res[idx];
    if (act) s = fmaxf(s, 0.f);
    C[idx] = s;
}

__global__ void add_kernel(const float* __restrict__ A, const float* __restrict__ B,
                           float* __restrict__ C, int n)
{
    int i = blockIdx.x * 256 + threadIdx.x;
    if (i < n) C[i] = A[i] + B[i];
}

// fused Q/K/V projection: 128 tokens x 384 outputs
__global__ void qkv_kernel(const float* __restrict__ X,
                           const float* __restrict__ Wq, const float* __restrict__ Wk,
                           const float* __restrict__ Wv, const float* __restrict__ bq,
                           const float* __restrict__ bk, const float* __restrict__ bv,
                           float* __restrict__ qm, float* __restrict__ km, float* __restrict__ vm)
{
    int idx = blockIdx.x * 256 + threadIdx.x;
    if (idx >= 128 * 384) return;
    int m = idx / 384, c = idx - m * 384;
    int sel = c >> 7, n = c & 127;
    const float* W = (sel == 0) ? Wq : (sel == 1) ? Wk : Wv;
    const float* b = (sel == 0) ? bq : (sel == 1) ? bk : bv;
    float s = b[n];
    const float* x = X + m * 128;
    #pragma unroll 8
    for (int k = 0; k < 128; ++k) s += x[k] * W[k * 128 + n];
    float* o = (sel == 0) ? qm : (sel == 1) ? km : vm;
    o[m * 128 + n] = s;
}

__global__ void attn_kernel(const float* __restrict__ q, const float* __restrict__ kmat,
                            const float* __restrict__ vmat, float* __restrict__ outp)
{
    __shared__ float p_s[128];
    __shared__ float red_s[4];
    const int tok = blockIdx.x;
    const int t = threadIdx.x;
    const int lane = t & 63, wid = t >> 6;
    for (int h = 0; h < 2; ++h) {
        const float* qr = q + tok * 128 + h * 64;
        const float* kr = kmat + t * 128 + h * 64;
        float s = 0.f;
        #pragma unroll
        for (int d = 0; d < 64; ++d) s += qr[d] * kr[d];
        s *= 0.125f;
        float m = s;
        #pragma unroll
        for (int o = 32; o; o >>= 1) m = fmaxf(m, __shfl_down(m, o, 64));
        if (lane == 0) red_s[wid] = m;
        __syncthreads();
        m = fmaxf(red_s[0], red_s[1]);
        float ev = expf(s - m);
        float ss = ev;
        #pragma unroll
        for (int o = 32; o; o >>= 1) ss += __shfl_down(ss, o, 64);
        if (lane == 0) red_s[2 + wid] = ss;
        __syncthreads();
        float tot = red_s[2] + red_s[3];
        p_s[t] = ev / tot;
        __syncthreads();
        if (t < 64) {
            float o = 0.f;
            #pragma unroll 8
            for (int j = 0; j < 128; ++j) o += p_s[j] * vmat[j * 128 + h * 64 + t];
            outp[tok * 128 + h * 64 + t] = o;
        }
        __syncthreads();
    }
}

__global__ void ln_kernel(const float* __restrict__ x, const float* __restrict__ g,
                          const float* __restrict__ b, float* __restrict__ y)
{
    __shared__ float red_s[4];
    const int row = blockIdx.x, t = threadIdx.x, lane = t & 63, wid = t >> 6;
    float v = x[row * 128 + t];
    float s = v;
    #pragma unroll
    for (int o = 32; o; o >>= 1) s += __shfl_down(s, o, 64);
    if (lane == 0) red_s[wid] = s;
    __syncthreads();
    float mean = (red_s[0] + red_s[1]) * (1.f / 128.f);
    float d = v - mean;
    float q2 = d * d;
    #pragma unroll
    for (int o = 32; o; o >>= 1) q2 += __shfl_down(q2, o, 64);
    if (lane == 0) red_s[2 + wid] = q2;
    __syncthreads();
    float var = (red_s[2] + red_s[3]) * (1.f / 128.f);
    y[row * 128 + t] = d * rsqrtf(var + 1e-5f) * g[t] + b[t];
}

// decode: 16 lanes per triple; U2 bf16 rows (16B/lane), Wf/V fp32
__global__ void __launch_bounds__(256) decode_kernel(
    const int* __restrict__ idx_i, const int* __restrict__ idx_j, const int* __restrict__ idx_k,
    const unsigned short* __restrict__ U2, const float* __restrict__ Wf, const float* __restrict__ V,
    const float* __restrict__ bias, float* __restrict__ out, int n)
{
    const int g = threadIdx.x >> 4;      // 0..15
    const int hl = threadIdx.x & 15;
    int t = blockIdx.x * 16 + g;
    if (t >= n) return;
    int i = idx_i[t], j = idx_j[t], kk = idx_k[t];
    const unsigned short* up = U2 + (long)i * 128 + hl * 8;
    const float* wp = Wf + kk * 128 + hl * 8;
    const float* vp = V + j * 128 + hl * 8;
    uint4 ur = *(const uint4*)up;                 // 8 bf16
    const unsigned short* uu = (const unsigned short*)&ur;
    float4 w0 = *(const float4*)wp,  w1 = *(const float4*)(wp + 4);
    float4 v0 = *(const float4*)vp,  v1 = *(const float4*)(vp + 4);
    float s = b2f(uu[0]) * w0.x * v0.x + b2f(uu[1]) * w0.y * v0.y
            + b2f(uu[2]) * w0.z * v0.z + b2f(uu[3]) * w0.w * v0.w
            + b2f(uu[4]) * w1.x * v1.x + b2f(uu[5]) * w1.y * v1.y
            + b2f(uu[6]) * w1.z * v1.z + b2f(uu[7]) * w1.w * v1.w;
    #pragma unroll
    for (int o = 8; o; o >>= 1) s += __shfl_down(s, o, 16);
    if (hl == 0) out[t] = 1.f / (1.f + expf(-(s + bias[0])));
}

// ---------------------------------------------------------------------------
extern "C" void kernel_launch(void* const* d_in, const int* in_sizes, int n_in,
                              void* d_out, int out_size, void* d_ws, size_t ws_size,
                              hipStream_t stream)
{
    const float* edge_x = (const float*)d_in[0];
    const int*   edge_i = (const int*)d_in[1];
    const int*   edge_k = (const int*)d_in[2];
    const int*   idx_i  = (const int*)d_in[3];
    const int*   idx_j  = (const int*)d_in[4];
    const int*   idx_k  = (const int*)d_in[5];
    const float* u0   = (const float*)d_in[6];
    const float* w0   = (const float*)d_in[7];
    const float* ep_W = (const float*)d_in[8];
    const float* ep_b = (const float*)d_in[9];
    const float* uW   = (const float*)d_in[10];
    const float* ub   = (const float*)d_in[11];
    const float* wW   = (const float*)d_in[12];
    const float* wb   = (const float*)d_in[13];
    const float* pos  = (const float*)d_in[14];
    const float* Wq = (const float*)d_in[15];
    const float* Wk = (const float*)d_in[16];
    const float* Wv = (const float*)d_in[17];
    const float* bq = (const float*)d_in[18];
    const float* bk = (const float*)d_in[19];
    const float* bv = (const float*)d_in[20];
    const float* Wo = (const float*)d_in[21];
    const float* bo = (const float*)d_in[22];
    const float* ln1_g = (const float*)d_in[23];
    const float* ln1_b = (const float*)d_in[24];
    const float* f_W1 = (const float*)d_in[25];
    const float* f_b1 = (const float*)d_in[26];
    const float* f_W2 = (const float*)d_in[27];
    const float* f_b2 = (const float*)d_in[28];
    const float* ln2_g = (const float*)d_in[29];
    const float* ln2_b = (const float*)d_in[30];
    const float* Vmat = (const float*)d_in[31];
    const float* bias = (const float*)d_in[32];

    const int E   = in_sizes[1];
    const int NTt = in_sizes[3];
    const int nNodes = in_sizes[6] / D_DIM;

    char* ws = (char*)d_ws;
    size_t off = 0;
    auto alloc = [&](size_t bytes) -> char* {
        char* p = ws + off;
        off = (off + bytes + 255) & ~(size_t)255;
        return p;
    };
    // zero-initialized region first (single memset)
    unsigned* Nmat32 = (unsigned*)alloc((size_t)nNodes * 128 * 4);
    float*    Xi     = (float*)alloc((size_t)nNodes * 64 * 4);
    float*    Xkseg  = (float*)alloc(128 * 64 * 4);
    unsigned* cntw   = (unsigned*)alloc(512);
    float*    Wmsg0  = (float*)alloc(65536);
    float*    Wmsg1  = (float*)alloc(65536);
    size_t zeroBytes = off;
    // rest (written before read)
    unsigned char* Nmat8 = (unsigned char*)alloc((size_t)nNodes * 128);
    float* cntraw = (float*)alloc((size_t)nNodes * 4);
    float* invcnt = (float*)alloc((size_t)nNodes * 4);
    unsigned short* U0b = (unsigned short*)alloc((size_t)nNodes * 128 * 2);
    unsigned short* U1b = (unsigned short*)alloc((size_t)nNodes * 128 * 2);
    unsigned short* U2b = (unsigned short*)alloc((size_t)nNodes * 128 * 2);
    float* partials = (float*)alloc((size_t)WB_BLOCKS * 16384 * 4);
    unsigned short* Bt0 = (unsigned short*)alloc(128 * 320 * 2);
    unsigned short* Bt1 = (unsigned short*)alloc(128 * 320 * 2);
    float* W1 = (float*)alloc(65536);
    float* W2 = (float*)alloc(65536);
    float* ebx0 = (float*)alloc(512);
    float* ebx1 = (float*)alloc(512);
    float* Wmsgn0 = (float*)alloc(65536);
    float* Wmsgn1 = (float*)alloc(65536);
    float* Xmat  = (float*)alloc(65536);
    float* qm    = (float*)alloc(65536);
    float* km    = (float*)alloc(65536);
    float* vm    = (float*)alloc(65536);
    float* attnO = (float*)alloc(65536);
    float* pre1  = (float*)alloc(65536);
    float* H1m   = (float*)alloc(65536);
    float* F1    = (float*)alloc(262144);
    float* pre2  = (float*)alloc(65536);
    float* Wfm   = (float*)alloc(65536);

    const float* uWt0 = uW;
    const float* uWb0 = uW + 128 * 128;
    const float* uWt1 = uW + 256 * 128;
    const float* uWb1 = uW + 256 * 128 + 128 * 128;
    const float* wWt0 = wW;
    const float* wWb0 = wW + 128 * 128;
    const float* wWt1 = wW + 256 * 128;
    const float* wWb1 = wW + 256 * 128 + 128 * 128;

    hipMemsetAsync(d_ws, 0, zeroBytes, stream);

    // ---- edge pass ----
    int epb = (E + 1023) / 1024;
    edge_pass_kernel<<<1024, 256, 0, stream>>>(edge_x, edge_i, edge_k, Xi, Xkseg,
                                               Nmat32, cntw, E, epb);
    cnt_kernel<<<(nNodes + 3) / 4, 256, 0, stream>>>(Nmat32, Nmat8, cntraw, invcnt, nNodes);
    u0cvt_kernel<<<1024, 256, 0, stream>>>(u0, U0b, (long)nNodes * 32);

    int npb = (nNodes + WB_BLOCKS - 1) / WB_BLOCKS;
    int la_grid = (nNodes + 127) / 128;

    // ---- layer 0 ----
    prep_kernel<<<161, 256, 0, stream>>>(uWt0, w0, uWb0, ep_W, ep_b, Bt0, ebx0);
    wmsgB_mfma<<<WB_BLOCKS, 256, 0, stream>>>(U0b, Nmat8, partials, npb, nNodes);
    reduceP_kernel<<<512, 256, 0, stream>>>(partials, Wmsg0);
    layerA_mfma<<<la_grid, 256, 0, stream>>>(U0b, Nmat8, Xi, cntraw, invcnt, Bt0, ub, ebx0, U1b, nNodes);
    wmsg_fin_kernel<<<64, 256, 0, stream>>>(Wmsg0, Xkseg, cntw, ep_W, ep_b, Wmsgn0);
    gemm_kernel<<<64, 256, 0, stream>>>(w0, wWt0, Wmsgn0, wWb0, wb, nullptr, W1, 128, 128, 128, 128, 1);

    // ---- layer 1 ----
    prep_kernel<<<161, 256, 0, stream>>>(uWt1, W1, uWb1, ep_W, ep_b, Bt1, ebx1);
    wmsgB_mfma<<<WB_BLOCKS, 256, 0, stream>>>(U1b, Nmat8, partials, npb, nNodes);
    reduceP_kernel<<<512, 256, 0, stream>>>(partials, Wmsg1);
    layerA_mfma<<<la_grid, 256, 0, stream>>>(U1b, Nmat8, Xi, cntraw, invcnt, Bt1, ub + 128, ebx1, U2b, nNodes);
    wmsg_fin_kernel<<<64, 256, 0, stream>>>(Wmsg1, Xkseg, cntw, ep_W, ep_b, Wmsgn1);
    gemm_kernel<<<64, 256, 0, stream>>>(W1, wWt1, Wmsgn1, wWb1, wb + 128, nullptr, W2, 128, 128, 128, 128, 1);

    // ---- TimeRefine ----
    add_kernel<<<64, 256, 0, stream>>>(W2, pos, Xmat, 128 * 128);
    qkv_kernel<<<192, 256, 0, stream>>>(Xmat, Wq, Wk, Wv, bq, bk, bv, qm, km, vm);
    attn_kernel<<<128, 128, 0, stream>>>(qm, km, vm, attnO);
    gemm_kernel<<<64, 256, 0, stream>>>(attnO, Wo, nullptr, nullptr, bo, Xmat, pre1, 128, 128, 128, 0, 0);
    ln_kernel<<<128, 128, 0, stream>>>(pre1, ln1_g, ln1_b, H1m);
    gemm_kernel<<<256, 256, 0, stream>>>(H1m, f_W1, nullptr, nullptr, f_b1, nullptr, F1, 128, 512, 128, 0, 1);
    gemm_kernel<<<64, 256, 0, stream>>>(F1, f_W2, nullptr, nullptr, f_b2, H1m, pre2, 128, 128, 512, 0, 0);
    ln_kernel<<<128, 128, 0, stream>>>(pre2, ln2_g, ln2_b, Wfm);

    // ---- decode ----
    decode_kernel<<<(NTt + 15) / 16, 256, 0, stream>>>(idx_i, idx_j, idx_k, U2b, Wfm, Vmat,
                                                       bias, (float*)d_out, NTt);
}